// Round 5
// baseline (1220.086 us; speedup 1.0000x reference)
//
#include <hip/hip_runtime.h>
#include <math.h>

#define B_  64
#define S_  128
#define LW_ 20
#define CHAR_E_ 30
#define CHAR_C_ 30
#define WORD_E_ 300
#define H_  256
#define NC_ 25
#define F_  330
#define KP_ 352       // K padded to multiple of 32
#define G4_ 1024      // 4*H
#define NG_ 2048      // both directions' gates

typedef __attribute__((ext_vector_type(8))) short short8;
typedef __attribute__((ext_vector_type(4))) float floatx4;

__device__ __forceinline__ float sigmoidf_(float x){ return 1.0f/(1.0f+__expf(-x)); }
__device__ __forceinline__ float tanh_(float x){ return 1.0f - 2.0f/(1.0f+__expf(2.0f*x)); }

__device__ __forceinline__ unsigned int f2bf(float f){
    unsigned int u = __float_as_uint(f);
    u += 0x7FFFu + ((u>>16)&1u);
    return (u>>16) & 0xFFFFu;
}

// ---------------- init: zero output scalar ----------------
__global__ void k_init(float* out){
    if(blockIdx.x==0 && threadIdx.x==0) *out = 0.f;
}

// ---------------- pack w_ih (f then r) into bf16 (2048 x 352), zero-padded ----------------
__global__ void k_pack(const float* wf, const float* wr, unsigned short* wp){
    int i = blockIdx.x*256 + threadIdx.x;
    if(i >= NG_*KP_) return;
    int r = i / KP_, k = i % KP_;
    const float* src = (r < G4_) ? wf : wr;
    int rr = r & (G4_-1);
    wp[i] = (k < F_) ? (unsigned short)f2bf(src[(size_t)rr*F_ + k]) : 0;
}

// ---------------- word embedding gather into feat cols [0,300) bf16, zeros [330,352) ----------------
__global__ void k_wemb(const float* wt, const int* sent, unsigned short* feat){
    int idx = blockIdx.x*256 + threadIdx.x;
    if(idx >= B_*S_*76) return;
    int n = idx / 76, e4 = idx % 76;
    if(e4 < 75){
        float4 v = ((const float4*)(wt + (size_t)sent[n]*WORD_E_))[e4];
        unsigned int lo = f2bf(v.x) | (f2bf(v.y)<<16);
        unsigned int hi = f2bf(v.z) | (f2bf(v.w)<<16);
        uint2 pr; pr.x = lo; pr.y = hi;
        *(uint2*)(feat + (size_t)n*KP_ + e4*4) = pr;
    } else {
        unsigned int* z = (unsigned int*)(feat + (size_t)n*KP_ + 330);
        #pragma unroll
        for(int q=0;q<11;q++) z[q] = 0;
    }
}

// ---------------- char conv + maxpool into feat cols [300,330) bf16 ----------------
__global__ void k_charconv(const float* ct, const int* word, const float* cw,
                           const float* cb, unsigned short* feat){
    __shared__ __align__(16) float x[8][32][20];   // [tok][ic][t]
    int tok0 = blockIdx.x*8;
    for(int e = threadIdx.x; e < 8*32*20; e += 256){
        int t  = e % 20;
        int ic = (e/20) & 31;
        int tl = e / 640;
        int id = word[(size_t)(tok0+tl)*LW_ + t];
        float v = 0.f;
        if(ic < CHAR_E_ && id != 0) v = ct[(size_t)id*CHAR_E_ + ic];
        x[tl][ic][t] = v;
    }
    __syncthreads();
    int tid = threadIdx.x;
    if(tid < 240){
        int tl = tid/30, oc = tid%30;
        float acc[22];
        #pragma unroll
        for(int q=0;q<22;q++) acc[q] = 0.f;
        for(int ic=0; ic<CHAR_E_; ic++){
            float w0 = cw[(oc*CHAR_E_+ic)*3+0];
            float w1 = cw[(oc*CHAR_E_+ic)*3+1];
            float w2 = cw[(oc*CHAR_E_+ic)*3+2];
            const float* xr = &x[tl][ic][0];
            #pragma unroll
            for(int t4=0;t4<5;t4++){
                float4 v = ((const float4*)xr)[t4];
                int t0 = t4*4;
                acc[t0+2] += v.x*w0; acc[t0+1] += v.x*w1; acc[t0+0] += v.x*w2;
                acc[t0+3] += v.y*w0; acc[t0+2] += v.y*w1; acc[t0+1] += v.y*w2;
                acc[t0+4] += v.z*w0; acc[t0+3] += v.z*w1; acc[t0+2] += v.z*w2;
                acc[t0+5] += v.w*w0; acc[t0+4] += v.w*w1; acc[t0+3] += v.w*w2;
            }
        }
        float m = -1e30f;
        #pragma unroll
        for(int t=0;t<20;t++){ float v = acc[t+1]; m = fmaxf(m, v); }
        m += cb[oc];
        feat[(size_t)(tok0+tl)*KP_ + WORD_E_ + oc] = (unsigned short)f2bf(m);
    }
}

// ---------------- bf16 MFMA GEMM: gx = feat(8192x352) . wpack(2048x352)^T + bias ----------------
// gx is written in LSTM-native layout: [dir][s][bg][tid(=wq*16+l16)][g*4+r]
__global__ __launch_bounds__(256) void k_gemm(const unsigned short* A, const unsigned short* Bw,
                                              const float* bf, const float* br, float* gx){
    __shared__ __align__(16) unsigned short As[64][40];
    __shared__ __align__(16) unsigned short Bs[64][40];
    int m0 = blockIdx.x*64, n0 = blockIdx.y*64;
    int tid = threadIdx.x;
    int w = tid>>6, lane = tid&63, q = lane>>4, l16 = lane&15;
    int srow = tid>>2, koff = (tid&3)*8;
    floatx4 acc0={0.f,0.f,0.f,0.f}, acc1=acc0, acc2=acc0, acc3=acc0;
    for(int k0=0; k0<KP_; k0+=32){
        uint4 av = *(const uint4*)(A  + (size_t)(m0+srow)*KP_ + k0 + koff);
        uint4 bv = *(const uint4*)(Bw + (size_t)(n0+srow)*KP_ + k0 + koff);
        __syncthreads();
        *(uint4*)&As[srow][koff] = av;
        *(uint4*)&Bs[srow][koff] = bv;
        __syncthreads();
        short8 af = *(const short8*)&As[w*16+l16][q*8];
        short8 b0 = *(const short8*)&Bs[l16][q*8];
        short8 b1 = *(const short8*)&Bs[16+l16][q*8];
        short8 b2 = *(const short8*)&Bs[32+l16][q*8];
        short8 b3 = *(const short8*)&Bs[48+l16][q*8];
        acc0 = __builtin_amdgcn_mfma_f32_16x16x32_bf16(af, b0, acc0, 0,0,0);
        acc1 = __builtin_amdgcn_mfma_f32_16x16x32_bf16(af, b1, acc1, 0,0,0);
        acc2 = __builtin_amdgcn_mfma_f32_16x16x32_bf16(af, b2, acc2, 0,0,0);
        acc3 = __builtin_amdgcn_mfma_f32_16x16x32_bf16(af, b3, acc3, 0,0,0);
    }
    // D layout: col = l16 -> n, row = q*4+r -> m
    #pragma unroll
    for(int nt=0; nt<4; nt++){
        floatx4 a = (nt==0)?acc0:(nt==1)?acc1:(nt==2)?acc2:acc3;
        int n = n0 + nt*16 + l16;
        int dirr = n >> 10, grow = n & 1023;
        int g  = grow >> 8, u = grow & 255;
        int wq = ((u >> 4) << 2) | ((u >> 2) & 3);   // w*4 + q
        int tr = u & 3;
        float bias = dirr ? br[grow] : bf[grow];
        #pragma unroll
        for(int r=0; r<4; r++){
            int m = m0 + w*16 + q*4 + r;
            int b = m >> 7, s = m & 127;
            size_t addr = ((((size_t)dirr*S_ + s)*4 + (b>>4))*1024 + wq*16 + (b&15))*16 + g*4 + tr;
            gx[addr] = a[r] + bias;
        }
    }
}

// ---------------- persistent biLSTM: one block per (dir, 16-batch group) ----------------
// 8 blocks x 1024 threads (16 waves). Whole-direction w_hh (1024x256) as fp8 e4m3
// (scaled x64) in 64 VGPRs/lane. h (scaled x16, fp8) in 4KB LDS. No cross-block sync.
// gx double-buffered in registers: step t+1 loads issued before step t's compute.
__global__ __launch_bounds__(1024,4) void k_lstm_all(const float* whhf, const float* whhr,
        const float* gx, float* hseq)
{
    int bid = blockIdx.x;        // 0..7
    int dir = bid >> 2;
    int bg  = bid & 3;
    int tid = threadIdx.x;
    int w    = tid >> 6;         // wave 0..15: units w*16..w*16+15
    int lane = tid & 63;
    int q    = lane >> 4;
    int l16  = lane & 15;

    __shared__ __align__(16) unsigned char hlds[16*264];   // [batch][unit] fp8, +8B row pad

    const float* whh = dir ? whhr : whhf;

    // one-time: convert my weight slice to fp8 A-fragments (rows g*256+w*16+l16, k=kt*32+q*8+j)
    long wreg[4][8];
    #pragma unroll
    for(int g=0; g<4; g++){
        const float* rp = whh + (size_t)(g*H_ + w*16 + l16)*H_;
        #pragma unroll
        for(int kt=0; kt<8; kt++){
            const float* p = rp + kt*32 + q*8;
            unsigned int d0 = 0, d1 = 0;
            d0 = __builtin_amdgcn_cvt_pk_fp8_f32(p[0]*64.f, p[1]*64.f, d0, false);
            d0 = __builtin_amdgcn_cvt_pk_fp8_f32(p[2]*64.f, p[3]*64.f, d0, true);
            d1 = __builtin_amdgcn_cvt_pk_fp8_f32(p[4]*64.f, p[5]*64.f, d1, false);
            d1 = __builtin_amdgcn_cvt_pk_fp8_f32(p[6]*64.f, p[7]*64.f, d1, true);
            wreg[g][kt] = (long)(((unsigned long long)d1 << 32) | d0);
        }
    }

    // zero h(t=-1)
    for(int i = tid; i < 16*264/4; i += 1024) ((unsigned int*)hlds)[i] = 0;
    __syncthreads();

    int b_glob = bg*16 + l16;
    int u0     = w*16 + q*4;
    const float inv_sc = 1.0f/1024.f;    // w x64, h x16

    float cc0=0.f, cc1=0.f, cc2=0.f, cc3=0.f;

    // gx slice for this thread: [s][16 floats], stride 4*1024*16 floats per s
    const float* gslice = gx + (((size_t)dir*S_*4 + bg)*1024 + tid)*16;
    #define GX_AT(s) (gslice + (size_t)(s)*(4*1024*16))

    // prefetch step 0
    int s0 = dir ? (S_-1) : 0;
    floatx4 gc0, gc1, gc2, gc3;
    {
        const float* gp = GX_AT(s0);
        gc0 = *(const floatx4*)(gp+0);
        gc1 = *(const floatx4*)(gp+4);
        gc2 = *(const floatx4*)(gp+8);
        gc3 = *(const floatx4*)(gp+12);
    }

    for(int t=0; t<S_; t++){
        int s = dir ? (S_-1-t) : t;

        // issue next step's loads first so their latency hides under this step's compute
        floatx4 gn0=gc0, gn1=gc1, gn2=gc2, gn3=gc3;
        if(t+1 < S_){
            const float* gp = GX_AT(dir ? (s-1) : (s+1));
            gn0 = *(const floatx4*)(gp+0);
            gn1 = *(const floatx4*)(gp+4);
            gn2 = *(const floatx4*)(gp+8);
            gn3 = *(const floatx4*)(gp+12);
        }

        floatx4 a0={0.f,0.f,0.f,0.f}, a1=a0, a2=a0, a3=a0;
        #pragma unroll
        for(int kt=0; kt<8; kt++){
            long hb = *(const long*)&hlds[l16*264 + kt*32 + q*8];
            a0 = __builtin_amdgcn_mfma_f32_16x16x32_fp8_fp8(wreg[0][kt], hb, a0, 0,0,0);
            a1 = __builtin_amdgcn_mfma_f32_16x16x32_fp8_fp8(wreg[1][kt], hb, a1, 0,0,0);
            a2 = __builtin_amdgcn_mfma_f32_16x16x32_fp8_fp8(wreg[2][kt], hb, a2, 0,0,0);
            a3 = __builtin_amdgcn_mfma_f32_16x16x32_fp8_fp8(wreg[3][kt], hb, a3, 0,0,0);
        }

        // cell update (C layout: col=l16=batch, row=q*4+r -> unit u0+r)
        float hv0, hv1, hv2, hv3;
        {
            float iv, fv, gv, ov, cn;
            iv=a0[0]*inv_sc+gc0[0]; fv=a1[0]*inv_sc+gc1[0]; gv=a2[0]*inv_sc+gc2[0]; ov=a3[0]*inv_sc+gc3[0];
            cn = sigmoidf_(fv)*cc0 + sigmoidf_(iv)*tanh_(gv); cc0=cn; hv0 = sigmoidf_(ov)*tanh_(cn);
            iv=a0[1]*inv_sc+gc0[1]; fv=a1[1]*inv_sc+gc1[1]; gv=a2[1]*inv_sc+gc2[1]; ov=a3[1]*inv_sc+gc3[1];
            cn = sigmoidf_(fv)*cc1 + sigmoidf_(iv)*tanh_(gv); cc1=cn; hv1 = sigmoidf_(ov)*tanh_(cn);
            iv=a0[2]*inv_sc+gc0[2]; fv=a1[2]*inv_sc+gc1[2]; gv=a2[2]*inv_sc+gc2[2]; ov=a3[2]*inv_sc+gc3[2];
            cn = sigmoidf_(fv)*cc2 + sigmoidf_(iv)*tanh_(gv); cc2=cn; hv2 = sigmoidf_(ov)*tanh_(cn);
            iv=a0[3]*inv_sc+gc0[3]; fv=a1[3]*inv_sc+gc1[3]; gv=a2[3]*inv_sc+gc2[3]; ov=a3[3]*inv_sc+gc3[3];
            cn = sigmoidf_(fv)*cc3 + sigmoidf_(iv)*tanh_(gv); cc3=cn; hv3 = sigmoidf_(ov)*tanh_(cn);
        }

        *(float4*)(hseq + (((size_t)dir*S_ + s)*B_ + b_glob)*H_ + u0) = make_float4(hv0,hv1,hv2,hv3);

        __syncthreads();   // everyone done reading h(t-1)
        unsigned int hd = 0;
        hd = __builtin_amdgcn_cvt_pk_fp8_f32(hv0*16.f, hv1*16.f, hd, false);
        hd = __builtin_amdgcn_cvt_pk_fp8_f32(hv2*16.f, hv3*16.f, hd, true);
        *(unsigned int*)&hlds[l16*264 + u0] = hd;
        __syncthreads();   // h(t) fully published

        gc0=gn0; gc1=gn1; gc2=gn2; gc3=gn3;
    }
    #undef GX_AT
}

// ---------------- emissions: block = 8 (s,b) pairs, h staged in LDS ----------------
__global__ __launch_bounds__(256) void k_em(const float* hseq, const float* lw, const float* lb, float* em){
    __shared__ __align__(16) float hb[8][516];   // +4 pad: conflict-free p-groups
    int sb0 = blockIdx.x*8;
    int tid = threadIdx.x;
    for(int i = tid; i < 1024; i += 256){
        int p = i >> 7, r = i & 127;
        int sb = sb0 + p, s = sb >> 6, b = sb & 63;
        const float* src = (r < 64) ? (hseq + (((size_t)0*S_+s)*B_+b)*H_ + r*4)
                                    : (hseq + (((size_t)1*S_+s)*B_+b)*H_ + (r-64)*4);
        *(float4*)&hb[p][r*4] = *(const float4*)src;
    }
    __syncthreads();
    if(tid < 200){
        int p = tid / 25, nc = tid % 25;
        const float4* wv = (const float4*)(lw + (size_t)nc*2*H_);
        const float4* hv = (const float4*)&hb[p][0];
        float acc = lb[nc];
        #pragma unroll 16
        for(int k=0;k<128;k++){ float4 a=hv[k], ww=wv[k]; acc += a.x*ww.x + a.y*ww.y + a.z*ww.z + a.w*ww.w; }
        em[(size_t)(sb0+p)*NC_ + nc] = acc;
    }
}

// ---------------- CRF NLL: one block (64 threads) per batch; out += logZ - score ----------------
__global__ void k_crf(const float* em, const int* tag, const void* mask,
                      const float* st, const float* et, const float* tr, float* out){
    __shared__ float trs[NC_*NC_];
    __shared__ float alpha[2][NC_];
    __shared__ float score_sh;
    __shared__ int   len_sh;
    int b = blockIdx.x, tid = threadIdx.x;
    for(int i=tid;i<NC_*NC_;i+=64) trs[i]=tr[i];
    unsigned int first = *(const unsigned int*)mask;
    int ml;  // 0=int32, 1=uint8, 2=float32
    if(first == 1u) ml = 0;
    else if(first == 0x3F800000u) ml = 2;
    else ml = 1;
    __syncthreads();

    float part = 0.f; int cnt = 0;
    for(int s = tid; s < S_; s += 64){
        float mkv;
        {
            int off = b*S_ + s;
            if(ml==0)      mkv = ((const int*)mask)[off] ? 1.f : 0.f;
            else if(ml==1) mkv = ((const unsigned char*)mask)[off] ? 1.f : 0.f;
            else           mkv = ((const float*)mask)[off];
        }
        cnt += (mkv != 0.f) ? 1 : 0;
        if(s == 0){
            int t0 = tag[b*S_];
            part += st[t0] + em[((size_t)0*B_ + b)*NC_ + t0];
        } else {
            int tp = tag[b*S_ + s-1], tc = tag[b*S_ + s];
            part += mkv * (trs[tp*NC_ + tc] + em[((size_t)s*B_ + b)*NC_ + tc]);
        }
    }
    for(int o=32;o>0;o>>=1){ part += __shfl_down(part, o); cnt += __shfl_down(cnt, o); }
    if(tid==0){ len_sh = cnt; score_sh = part; }
    __syncthreads();
    float score = 0.f;
    if(tid == 0){
        int last = len_sh - 1;
        score = score_sh + et[ tag[b*S_ + last] ];
    }

    if(tid < NC_) alpha[0][tid] = st[tid] + em[((size_t)0*B_ + b)*NC_ + tid];
    __syncthreads();
    int cur = 0;
    for(int s=1;s<S_;s++){
        float nv = 0.f;
        if(tid < NC_){
            int j = tid;
            float m = -1e30f;
            #pragma unroll
            for(int i=0;i<NC_;i++){ float v = alpha[cur][i] + trs[i*NC_+j]; m = fmaxf(m, v); }
            float sum = 0.f;
            #pragma unroll
            for(int i=0;i<NC_;i++){ sum += __expf(alpha[cur][i] + trs[i*NC_+j] - m); }
            float nxt = m + __logf(sum) + em[((size_t)s*B_ + b)*NC_ + j];
            float mkv;
            {
                int off = b*S_ + s;
                if(ml==0)      mkv = ((const int*)mask)[off] ? 1.f : 0.f;
                else if(ml==1) mkv = ((const unsigned char*)mask)[off] ? 1.f : 0.f;
                else           mkv = ((const float*)mask)[off];
            }
            nv = (mkv != 0.f) ? nxt : alpha[cur][j];
        }
        __syncthreads();
        if(tid < NC_) alpha[cur^1][tid] = nv;
        __syncthreads();
        cur ^= 1;
    }
    float v = (tid < NC_) ? (alpha[cur][tid] + et[tid]) : -1e30f;
    float m = v;
    for(int o=32;o>0;o>>=1) m = fmaxf(m, __shfl_down(m, o));
    m = __shfl(m, 0);
    float e = (tid < NC_) ? __expf(v - m) : 0.f;
    for(int o=32;o>0;o>>=1) e += __shfl_down(e, o);
    if(tid == 0){
        float logZ = m + __logf(e);
        atomicAdd(out, logZ - score);
    }
}

extern "C" void kernel_launch(void* const* d_in, const int* in_sizes, int n_in,
                              void* d_out, int out_size, void* d_ws, size_t ws_size,
                              hipStream_t stream) {
    const float* word_table = (const float*)d_in[0];
    const float* char_table = (const float*)d_in[1];
    const float* conv_w     = (const float*)d_in[2];
    const float* conv_b     = (const float*)d_in[3];
    const float* w_ih_f     = (const float*)d_in[4];
    const float* w_hh_f     = (const float*)d_in[5];
    const float* b_f        = (const float*)d_in[6];
    const float* w_ih_r     = (const float*)d_in[7];
    const float* w_hh_r     = (const float*)d_in[8];
    const float* b_r        = (const float*)d_in[9];
    const float* lin_w      = (const float*)d_in[10];
    const float* lin_b      = (const float*)d_in[11];
    const float* start_t    = (const float*)d_in[12];
    const float* end_t      = (const float*)d_in[13];
    const float* trans      = (const float*)d_in[14];
    const int*   sent       = (const int*)d_in[15];
    const int*   word       = (const int*)d_in[16];
    const int*   tag        = (const int*)d_in[17];
    const void*  mask       = d_in[18];
    float* out = (float*)d_out;

    char* ws = (char*)d_ws;
    unsigned short* feat  = (unsigned short*)ws;                 // 8192*352*2  = 5,767,168 B
    unsigned short* wpack = (unsigned short*)(ws + 5767168);     // 2048*352*2  = 1,441,792 B
    float* gx   = (float*)(ws + 5767168 + 1441792);              // 16,777,216 f = 67,108,864 B
    float* hseq = (float*)(ws + 5767168 + 1441792 + 67108864);   // 4,194,304 f = 16,777,216 B
    float* em   = (float*)(ws + 5767168 + 1441792 + 67108864 + 16777216);  // 204,800 f

    k_init<<<dim3(1), 64, 0, stream>>>(out);
    k_pack<<<dim3((NG_*KP_+255)/256), 256, 0, stream>>>(w_ih_f, w_ih_r, wpack);
    k_wemb<<<dim3((B_*S_*76+255)/256), 256, 0, stream>>>(word_table, sent, feat);
    k_charconv<<<dim3(B_*S_/8), 256, 0, stream>>>(char_table, word, conv_w, conv_b, feat);
    k_gemm<<<dim3(B_*S_/64, NG_/64), 256, 0, stream>>>(feat, wpack, b_f, b_r, gx);
    k_lstm_all<<<dim3(8), 1024, 0, stream>>>(w_hh_f, w_hh_r, gx, hseq);
    k_em<<<dim3(S_*B_/8), 256, 0, stream>>>(hseq, lin_w, lin_b, em);
    k_crf<<<dim3(B_), 64, 0, stream>>>(em, tag, mask, start_t, end_t, trans, out);
}

// Round 6
// 930.165 us; speedup vs baseline: 1.3117x; 1.3117x over previous
//
#include <hip/hip_runtime.h>
#include <math.h>

#define B_  64
#define S_  128
#define LW_ 20
#define CHAR_E_ 30
#define CHAR_C_ 30
#define WORD_E_ 300
#define H_  256
#define NC_ 25
#define F_  330
#define KP_ 352       // K padded to multiple of 32
#define G4_ 1024      // 4*H
#define NG_ 2048      // both directions' gates

typedef __attribute__((ext_vector_type(8))) short short8;
typedef __attribute__((ext_vector_type(4))) float floatx4;

__device__ __forceinline__ float sigmoidf_(float x){ return 1.0f/(1.0f+__expf(-x)); }
__device__ __forceinline__ float tanh_(float x){ return 1.0f - 2.0f/(1.0f+__expf(2.0f*x)); }

__device__ __forceinline__ unsigned int f2bf(float f){
    unsigned int u = __float_as_uint(f);
    u += 0x7FFFu + ((u>>16)&1u);
    return (u>>16) & 0xFFFFu;
}
__device__ __forceinline__ float bflo(unsigned int v){ return __uint_as_float(v<<16); }
__device__ __forceinline__ float bfhi(unsigned int v){ return __uint_as_float(v & 0xFFFF0000u); }

// LDS-only barrier: does NOT drain vmcnt, so global prefetch loads stay in flight.
#define BAR_LDS() __asm__ volatile("s_waitcnt lgkmcnt(0)\n\ts_barrier" ::: "memory")

// ---------------- init: zero output scalar ----------------
__global__ void k_init(float* out){
    if(blockIdx.x==0 && threadIdx.x==0) *out = 0.f;
}

// ---------------- pack w_ih (f then r) into bf16 (2048 x 352), zero-padded ----------------
__global__ void k_pack(const float* wf, const float* wr, unsigned short* wp){
    int i = blockIdx.x*256 + threadIdx.x;
    if(i >= NG_*KP_) return;
    int r = i / KP_, k = i % KP_;
    const float* src = (r < G4_) ? wf : wr;
    int rr = r & (G4_-1);
    wp[i] = (k < F_) ? (unsigned short)f2bf(src[(size_t)rr*F_ + k]) : 0;
}

// ---------------- word embedding gather into feat cols [0,300) bf16, zeros [330,352) ----------------
__global__ void k_wemb(const float* wt, const int* sent, unsigned short* feat){
    int idx = blockIdx.x*256 + threadIdx.x;
    if(idx >= B_*S_*76) return;
    int n = idx / 76, e4 = idx % 76;
    if(e4 < 75){
        float4 v = ((const float4*)(wt + (size_t)sent[n]*WORD_E_))[e4];
        unsigned int lo = f2bf(v.x) | (f2bf(v.y)<<16);
        unsigned int hi = f2bf(v.z) | (f2bf(v.w)<<16);
        uint2 pr; pr.x = lo; pr.y = hi;
        *(uint2*)(feat + (size_t)n*KP_ + e4*4) = pr;
    } else {
        unsigned int* z = (unsigned int*)(feat + (size_t)n*KP_ + 330);
        #pragma unroll
        for(int q=0;q<11;q++) z[q] = 0;
    }
}

// ---------------- char conv + maxpool into feat cols [300,330) bf16 ----------------
__global__ void k_charconv(const float* ct, const int* word, const float* cw,
                           const float* cb, unsigned short* feat){
    __shared__ __align__(16) float x[8][32][20];   // [tok][ic][t]
    int tok0 = blockIdx.x*8;
    for(int e = threadIdx.x; e < 8*32*20; e += 256){
        int t  = e % 20;
        int ic = (e/20) & 31;
        int tl = e / 640;
        int id = word[(size_t)(tok0+tl)*LW_ + t];
        float v = 0.f;
        if(ic < CHAR_E_ && id != 0) v = ct[(size_t)id*CHAR_E_ + ic];
        x[tl][ic][t] = v;
    }
    __syncthreads();
    int tid = threadIdx.x;
    if(tid < 240){
        int tl = tid/30, oc = tid%30;
        float acc[22];
        #pragma unroll
        for(int q=0;q<22;q++) acc[q] = 0.f;
        for(int ic=0; ic<CHAR_E_; ic++){
            float w0 = cw[(oc*CHAR_E_+ic)*3+0];
            float w1 = cw[(oc*CHAR_E_+ic)*3+1];
            float w2 = cw[(oc*CHAR_E_+ic)*3+2];
            const float* xr = &x[tl][ic][0];
            #pragma unroll
            for(int t4=0;t4<5;t4++){
                float4 v = ((const float4*)xr)[t4];
                int t0 = t4*4;
                acc[t0+2] += v.x*w0; acc[t0+1] += v.x*w1; acc[t0+0] += v.x*w2;
                acc[t0+3] += v.y*w0; acc[t0+2] += v.y*w1; acc[t0+1] += v.y*w2;
                acc[t0+4] += v.z*w0; acc[t0+3] += v.z*w1; acc[t0+2] += v.z*w2;
                acc[t0+5] += v.w*w0; acc[t0+4] += v.w*w1; acc[t0+3] += v.w*w2;
            }
        }
        float m = -1e30f;
        #pragma unroll
        for(int t=0;t<20;t++){ float v = acc[t+1]; m = fmaxf(m, v); }
        m += cb[oc];
        feat[(size_t)(tok0+tl)*KP_ + WORD_E_ + oc] = (unsigned short)f2bf(m);
    }
}

// ---------------- bf16 MFMA GEMM: gx(bf16) = feat(8192x352) . wpack(2048x352)^T + bias ----------------
// gx layout: [dir][s][b][grow] bf16 (lane-coalesced-ish short stores)
__global__ __launch_bounds__(256) void k_gemm(const unsigned short* A, const unsigned short* Bw,
                                              const float* bf, const float* br, unsigned short* gxb){
    __shared__ __align__(16) unsigned short As[64][40];
    __shared__ __align__(16) unsigned short Bs[64][40];
    int m0 = blockIdx.x*64, n0 = blockIdx.y*64;
    int tid = threadIdx.x;
    int w = tid>>6, lane = tid&63, q = lane>>4, l16 = lane&15;
    int srow = tid>>2, koff = (tid&3)*8;
    floatx4 acc0={0.f,0.f,0.f,0.f}, acc1=acc0, acc2=acc0, acc3=acc0;
    for(int k0=0; k0<KP_; k0+=32){
        uint4 av = *(const uint4*)(A  + (size_t)(m0+srow)*KP_ + k0 + koff);
        uint4 bv = *(const uint4*)(Bw + (size_t)(n0+srow)*KP_ + k0 + koff);
        __syncthreads();
        *(uint4*)&As[srow][koff] = av;
        *(uint4*)&Bs[srow][koff] = bv;
        __syncthreads();
        short8 af = *(const short8*)&As[w*16+l16][q*8];
        short8 b0 = *(const short8*)&Bs[l16][q*8];
        short8 b1 = *(const short8*)&Bs[16+l16][q*8];
        short8 b2 = *(const short8*)&Bs[32+l16][q*8];
        short8 b3 = *(const short8*)&Bs[48+l16][q*8];
        acc0 = __builtin_amdgcn_mfma_f32_16x16x32_bf16(af, b0, acc0, 0,0,0);
        acc1 = __builtin_amdgcn_mfma_f32_16x16x32_bf16(af, b1, acc1, 0,0,0);
        acc2 = __builtin_amdgcn_mfma_f32_16x16x32_bf16(af, b2, acc2, 0,0,0);
        acc3 = __builtin_amdgcn_mfma_f32_16x16x32_bf16(af, b3, acc3, 0,0,0);
    }
    // D layout: col = l16 -> n, row = q*4+r -> m
    #pragma unroll
    for(int nt=0; nt<4; nt++){
        floatx4 a = (nt==0)?acc0:(nt==1)?acc1:(nt==2)?acc2:acc3;
        int n = n0 + nt*16 + l16;
        int dirr = n >> 10, grow = n & 1023;
        float bias = dirr ? br[grow] : bf[grow];
        #pragma unroll
        for(int r=0; r<4; r++){
            int m = m0 + w*16 + q*4 + r;
            int b = m >> 7, s = m & 127;
            gxb[(((size_t)dirr*S_ + s)*B_ + b)*G4_ + grow] = (unsigned short)f2bf(a[r] + bias);
        }
    }
}

// ---------------- persistent biLSTM: 32 blocks x 1024 threads ----------------
// block = (dir, 4-batch group). Full-direction w_hh (1024x256) as fp8 e4m3 (x64)
// in 64 VGPRs/lane. h (fp8, x16) in 4KB LDS. No cross-block sync; raw lgkm-only
// barriers keep gx prefetch loads in flight across steps.
__global__ __launch_bounds__(1024,1) void k_lstm_all(const float* whhf, const float* whhr,
        const unsigned short* gxb, float* hseq)
{
    int bid = blockIdx.x;        // 0..31
    int dir = bid >> 4;
    int bg  = bid & 15;          // 4 batches: bg*4 .. bg*4+3
    int tid = threadIdx.x;
    int w    = tid >> 6;         // wave 0..15: units w*16..w*16+15
    int lane = tid & 63;
    int q    = lane >> 4;
    int l16  = lane & 15;

    __shared__ __align__(16) unsigned char hlds[16*264];   // rows 0..3 = batches, rest stay 0

    const float* whh = dir ? whhr : whhf;

    // one-time: convert my weight slice to fp8 A-fragments (rows g*256+w*16+l16, k=kt*32+q*8+j)
    long wreg[4][8];
    #pragma unroll
    for(int g=0; g<4; g++){
        const float* rp = whh + (size_t)(g*H_ + w*16 + l16)*H_;
        #pragma unroll
        for(int kt=0; kt<8; kt++){
            const float* p = rp + kt*32 + q*8;
            unsigned int d0 = 0, d1 = 0;
            d0 = __builtin_amdgcn_cvt_pk_fp8_f32(p[0]*64.f, p[1]*64.f, d0, false);
            d0 = __builtin_amdgcn_cvt_pk_fp8_f32(p[2]*64.f, p[3]*64.f, d0, true);
            d1 = __builtin_amdgcn_cvt_pk_fp8_f32(p[4]*64.f, p[5]*64.f, d1, false);
            d1 = __builtin_amdgcn_cvt_pk_fp8_f32(p[6]*64.f, p[7]*64.f, d1, true);
            wreg[g][kt] = (long)(((unsigned long long)d1 << 32) | d0);
        }
    }

    for(int i = tid; i < 16*264/4; i += 1024) ((unsigned int*)hlds)[i] = 0;
    __syncthreads();

    int act     = (l16 < 4);
    int b_glob  = bg*4 + l16;                 // valid when act
    int u0      = w*16 + q*4;                 // unit base (rows q*4+r of D)
    const float inv_sc = 1.0f/1024.f;         // w x64, h x16

    float cc0=0.f, cc1=0.f, cc2=0.f, cc3=0.f;

    uint2 gc0={0,0}, gc1={0,0}, gc2={0,0}, gc3={0,0};
    uint2 gn0={0,0}, gn1={0,0}, gn2={0,0}, gn3={0,0};
    {
        int s0 = dir ? (S_-1) : 0;
        if(act){
            const unsigned short* gp = gxb + (((size_t)dir*S_ + s0)*B_ + b_glob)*G4_ + u0;
            gc0 = *(const uint2*)(gp);
            gc1 = *(const uint2*)(gp + 256);
            gc2 = *(const uint2*)(gp + 512);
            gc3 = *(const uint2*)(gp + 768);
        }
    }

    for(int t=0; t<S_; t++){
        int s = dir ? (S_-1-t) : t;

        // prefetch step t+1's gates (loads stay in flight across the lgkm-only barriers)
        if(t+1 < S_){
            if(act){
                int sn = dir ? (s-1) : (s+1);
                const unsigned short* gp = gxb + (((size_t)dir*S_ + sn)*B_ + b_glob)*G4_ + u0;
                gn0 = *(const uint2*)(gp);
                gn1 = *(const uint2*)(gp + 256);
                gn2 = *(const uint2*)(gp + 512);
                gn3 = *(const uint2*)(gp + 768);
            }
        }

        // gates = W @ h(t-1)
        floatx4 a0={0.f,0.f,0.f,0.f}, a1=a0, a2=a0, a3=a0;
        #pragma unroll
        for(int kt=0; kt<8; kt++){
            long hb = *(const long*)&hlds[l16*264 + kt*32 + q*8];
            a0 = __builtin_amdgcn_mfma_f32_16x16x32_fp8_fp8(wreg[0][kt], hb, a0, 0,0,0);
            a1 = __builtin_amdgcn_mfma_f32_16x16x32_fp8_fp8(wreg[1][kt], hb, a1, 0,0,0);
            a2 = __builtin_amdgcn_mfma_f32_16x16x32_fp8_fp8(wreg[2][kt], hb, a2, 0,0,0);
            a3 = __builtin_amdgcn_mfma_f32_16x16x32_fp8_fp8(wreg[3][kt], hb, a3, 0,0,0);
        }

        BAR_LDS();   // all waves done reading h(t-1)

        if(act){
            float i0=bflo(gc0.x), i1=bfhi(gc0.x), i2=bflo(gc0.y), i3=bfhi(gc0.y);
            float f0=bflo(gc1.x), f1=bfhi(gc1.x), f2=bflo(gc1.y), f3=bfhi(gc1.y);
            float g0=bflo(gc2.x), g1=bfhi(gc2.x), g2=bflo(gc2.y), g3=bfhi(gc2.y);
            float o0=bflo(gc3.x), o1=bfhi(gc3.x), o2=bflo(gc3.y), o3=bfhi(gc3.y);
            float iv, fv, gv, ov, cn;
            float hv0, hv1, hv2, hv3;
            iv=a0[0]*inv_sc+i0; fv=a1[0]*inv_sc+f0; gv=a2[0]*inv_sc+g0; ov=a3[0]*inv_sc+o0;
            cn = sigmoidf_(fv)*cc0 + sigmoidf_(iv)*tanh_(gv); cc0=cn; hv0 = sigmoidf_(ov)*tanh_(cn);
            iv=a0[1]*inv_sc+i1; fv=a1[1]*inv_sc+f1; gv=a2[1]*inv_sc+g1; ov=a3[1]*inv_sc+o1;
            cn = sigmoidf_(fv)*cc1 + sigmoidf_(iv)*tanh_(gv); cc1=cn; hv1 = sigmoidf_(ov)*tanh_(cn);
            iv=a0[2]*inv_sc+i2; fv=a1[2]*inv_sc+f2; gv=a2[2]*inv_sc+g2; ov=a3[2]*inv_sc+o2;
            cn = sigmoidf_(fv)*cc2 + sigmoidf_(iv)*tanh_(gv); cc2=cn; hv2 = sigmoidf_(ov)*tanh_(cn);
            iv=a0[3]*inv_sc+i3; fv=a1[3]*inv_sc+f3; gv=a2[3]*inv_sc+g3; ov=a3[3]*inv_sc+o3;
            cn = sigmoidf_(fv)*cc3 + sigmoidf_(iv)*tanh_(gv); cc3=cn; hv3 = sigmoidf_(ov)*tanh_(cn);

            *(float4*)(hseq + (((size_t)dir*S_ + s)*B_ + b_glob)*H_ + u0) = make_float4(hv0,hv1,hv2,hv3);

            unsigned int hd = 0;
            hd = __builtin_amdgcn_cvt_pk_fp8_f32(hv0*16.f, hv1*16.f, hd, false);
            hd = __builtin_amdgcn_cvt_pk_fp8_f32(hv2*16.f, hv3*16.f, hd, true);
            *(unsigned int*)&hlds[l16*264 + u0] = hd;
        }

        BAR_LDS();   // h(t) visible to all waves

        gc0=gn0; gc1=gn1; gc2=gn2; gc3=gn3;
    }
}

// ---------------- emissions: block = 8 (s,b) pairs, h staged in LDS ----------------
__global__ __launch_bounds__(256) void k_em(const float* hseq, const float* lw, const float* lb, float* em){
    __shared__ __align__(16) float hb[8][516];   // +4 pad
    int sb0 = blockIdx.x*8;
    int tid = threadIdx.x;
    for(int i = tid; i < 1024; i += 256){
        int p = i >> 7, r = i & 127;
        int sb = sb0 + p, s = sb >> 6, b = sb & 63;
        const float* src = (r < 64) ? (hseq + (((size_t)0*S_+s)*B_+b)*H_ + r*4)
                                    : (hseq + (((size_t)1*S_+s)*B_+b)*H_ + (r-64)*4);
        *(float4*)&hb[p][r*4] = *(const float4*)src;
    }
    __syncthreads();
    if(tid < 200){
        int p = tid / 25, nc = tid % 25;
        const float4* wv = (const float4*)(lw + (size_t)nc*2*H_);
        const float4* hv = (const float4*)&hb[p][0];
        float acc = lb[nc];
        #pragma unroll 16
        for(int k=0;k<128;k++){ float4 a=hv[k], ww=wv[k]; acc += a.x*ww.x + a.y*ww.y + a.z*ww.z + a.w*ww.w; }
        em[(size_t)(sb0+p)*NC_ + nc] = acc;
    }
}

// ---------------- CRF NLL: one block (64 threads) per batch; out += logZ - score ----------------
__global__ void k_crf(const float* em, const int* tag, const void* mask,
                      const float* st, const float* et, const float* tr, float* out){
    __shared__ float trs[NC_*NC_];
    __shared__ float alpha[2][NC_];
    __shared__ float score_sh;
    __shared__ int   len_sh;
    int b = blockIdx.x, tid = threadIdx.x;
    for(int i=tid;i<NC_*NC_;i+=64) trs[i]=tr[i];
    unsigned int first = *(const unsigned int*)mask;
    int ml;  // 0=int32, 1=uint8, 2=float32
    if(first == 1u) ml = 0;
    else if(first == 0x3F800000u) ml = 2;
    else ml = 1;
    __syncthreads();

    float part = 0.f; int cnt = 0;
    for(int s = tid; s < S_; s += 64){
        float mkv;
        {
            int off = b*S_ + s;
            if(ml==0)      mkv = ((const int*)mask)[off] ? 1.f : 0.f;
            else if(ml==1) mkv = ((const unsigned char*)mask)[off] ? 1.f : 0.f;
            else           mkv = ((const float*)mask)[off];
        }
        cnt += (mkv != 0.f) ? 1 : 0;
        if(s == 0){
            int t0 = tag[b*S_];
            part += st[t0] + em[((size_t)0*B_ + b)*NC_ + t0];
        } else {
            int tp = tag[b*S_ + s-1], tc = tag[b*S_ + s];
            part += mkv * (trs[tp*NC_ + tc] + em[((size_t)s*B_ + b)*NC_ + tc]);
        }
    }
    for(int o=32;o>0;o>>=1){ part += __shfl_down(part, o); cnt += __shfl_down(cnt, o); }
    if(tid==0){ len_sh = cnt; score_sh = part; }
    __syncthreads();
    float score = 0.f;
    if(tid == 0){
        int last = len_sh - 1;
        score = score_sh + et[ tag[b*S_ + last] ];
    }

    if(tid < NC_) alpha[0][tid] = st[tid] + em[((size_t)0*B_ + b)*NC_ + tid];
    __syncthreads();
    int cur = 0;
    for(int s=1;s<S_;s++){
        float nv = 0.f;
        if(tid < NC_){
            int j = tid;
            float m = -1e30f;
            #pragma unroll
            for(int i=0;i<NC_;i++){ float v = alpha[cur][i] + trs[i*NC_+j]; m = fmaxf(m, v); }
            float sum = 0.f;
            #pragma unroll
            for(int i=0;i<NC_;i++){ sum += __expf(alpha[cur][i] + trs[i*NC_+j] - m); }
            float nxt = m + __logf(sum) + em[((size_t)s*B_ + b)*NC_ + j];
            float mkv;
            {
                int off = b*S_ + s;
                if(ml==0)      mkv = ((const int*)mask)[off] ? 1.f : 0.f;
                else if(ml==1) mkv = ((const unsigned char*)mask)[off] ? 1.f : 0.f;
                else           mkv = ((const float*)mask)[off];
            }
            nv = (mkv != 0.f) ? nxt : alpha[cur][j];
        }
        __syncthreads();
        if(tid < NC_) alpha[cur^1][tid] = nv;
        __syncthreads();
        cur ^= 1;
    }
    float v = (tid < NC_) ? (alpha[cur][tid] + et[tid]) : -1e30f;
    float m = v;
    for(int o=32;o>0;o>>=1) m = fmaxf(m, __shfl_down(m, o));
    m = __shfl(m, 0);
    float e = (tid < NC_) ? __expf(v - m) : 0.f;
    for(int o=32;o>0;o>>=1) e += __shfl_down(e, o);
    if(tid == 0){
        float logZ = m + __logf(e);
        atomicAdd(out, logZ - score);
    }
}

extern "C" void kernel_launch(void* const* d_in, const int* in_sizes, int n_in,
                              void* d_out, int out_size, void* d_ws, size_t ws_size,
                              hipStream_t stream) {
    const float* word_table = (const float*)d_in[0];
    const float* char_table = (const float*)d_in[1];
    const float* conv_w     = (const float*)d_in[2];
    const float* conv_b     = (const float*)d_in[3];
    const float* w_ih_f     = (const float*)d_in[4];
    const float* w_hh_f     = (const float*)d_in[5];
    const float* b_f        = (const float*)d_in[6];
    const float* w_ih_r     = (const float*)d_in[7];
    const float* w_hh_r     = (const float*)d_in[8];
    const float* b_r        = (const float*)d_in[9];
    const float* lin_w      = (const float*)d_in[10];
    const float* lin_b      = (const float*)d_in[11];
    const float* start_t    = (const float*)d_in[12];
    const float* end_t      = (const float*)d_in[13];
    const float* trans      = (const float*)d_in[14];
    const int*   sent       = (const int*)d_in[15];
    const int*   word       = (const int*)d_in[16];
    const int*   tag        = (const int*)d_in[17];
    const void*  mask       = d_in[18];
    float* out = (float*)d_out;

    char* ws = (char*)d_ws;
    unsigned short* feat  = (unsigned short*)ws;                 // 8192*352*2   = 5,767,168 B
    unsigned short* wpack = (unsigned short*)(ws + 5767168);     // 2048*352*2   = 1,441,792 B
    unsigned short* gxb   = (unsigned short*)(ws + 5767168 + 1441792);           // 2*128*64*1024*2 = 33,554,432 B
    float* hseq = (float*)(ws + 5767168 + 1441792 + 33554432);   // 4,194,304 f  = 16,777,216 B
    float* em   = (float*)(ws + 5767168 + 1441792 + 33554432 + 16777216);        // 204,800 f

    k_init<<<dim3(1), 64, 0, stream>>>(out);
    k_pack<<<dim3((NG_*KP_+255)/256), 256, 0, stream>>>(w_ih_f, w_ih_r, wpack);
    k_wemb<<<dim3((B_*S_*76+255)/256), 256, 0, stream>>>(word_table, sent, feat);
    k_charconv<<<dim3(B_*S_/8), 256, 0, stream>>>(char_table, word, conv_w, conv_b, feat);
    k_gemm<<<dim3(B_*S_/64, NG_/64), 256, 0, stream>>>(feat, wpack, b_f, b_r, gxb);
    k_lstm_all<<<dim3(32), 1024, 0, stream>>>(w_hh_f, w_hh_r, gxb, hseq);
    k_em<<<dim3(S_*B_/8), 256, 0, stream>>>(hseq, lin_w, lin_b, em);
    k_crf<<<dim3(B_), 64, 0, stream>>>(em, tag, mask, start_t, end_t, trans, out);
}

// Round 7
// 710.230 us; speedup vs baseline: 1.7179x; 1.3097x over previous
//
#include <hip/hip_runtime.h>
#include <math.h>

#define B_  64
#define S_  128
#define LW_ 20
#define CHAR_E_ 30
#define CHAR_C_ 30
#define WORD_E_ 300
#define H_  256
#define NC_ 25
#define F_  330
#define KP_ 352       // K padded to multiple of 32
#define G4_ 1024      // 4*H
#define NG_ 2048      // both directions' gates

typedef __attribute__((ext_vector_type(8))) short short8;
typedef __attribute__((ext_vector_type(4))) float floatx4;

__device__ __forceinline__ float sigmoidf_(float x){ return 1.0f/(1.0f+__expf(-x)); }
__device__ __forceinline__ float tanh_(float x){ return 1.0f - 2.0f/(1.0f+__expf(2.0f*x)); }

__device__ __forceinline__ unsigned int f2bf(float f){
    unsigned int u = __float_as_uint(f);
    u += 0x7FFFu + ((u>>16)&1u);
    return (u>>16) & 0xFFFFu;
}
__device__ __forceinline__ float bf2f(unsigned int v){ return __uint_as_float(v<<16); }

// LDS-only barrier: does NOT drain vmcnt, so global prefetch loads stay in flight.
#define BAR_LDS() __asm__ volatile("s_waitcnt lgkmcnt(0)\n\ts_barrier" ::: "memory")

// ---------------- init: zero output scalar ----------------
__global__ void k_init(float* out){
    if(blockIdx.x==0 && threadIdx.x==0) *out = 0.f;
}

// ---------------- pack w_ih (f then r) into bf16 (2048 x 352), zero-padded ----------------
__global__ void k_pack(const float* wf, const float* wr, unsigned short* wp){
    int i = blockIdx.x*256 + threadIdx.x;
    if(i >= NG_*KP_) return;
    int r = i / KP_, k = i % KP_;
    const float* src = (r < G4_) ? wf : wr;
    int rr = r & (G4_-1);
    wp[i] = (k < F_) ? (unsigned short)f2bf(src[(size_t)rr*F_ + k]) : 0;
}

// ---------------- word embedding gather into feat cols [0,300) bf16, zeros [330,352) ----------------
__global__ void k_wemb(const float* wt, const int* sent, unsigned short* feat){
    int idx = blockIdx.x*256 + threadIdx.x;
    if(idx >= B_*S_*76) return;
    int n = idx / 76, e4 = idx % 76;
    if(e4 < 75){
        float4 v = ((const float4*)(wt + (size_t)sent[n]*WORD_E_))[e4];
        unsigned int lo = f2bf(v.x) | (f2bf(v.y)<<16);
        unsigned int hi = f2bf(v.z) | (f2bf(v.w)<<16);
        uint2 pr; pr.x = lo; pr.y = hi;
        *(uint2*)(feat + (size_t)n*KP_ + e4*4) = pr;
    } else {
        unsigned int* z = (unsigned int*)(feat + (size_t)n*KP_ + 330);
        #pragma unroll
        for(int q=0;q<11;q++) z[q] = 0;
    }
}

// ---------------- char conv + maxpool into feat cols [300,330) bf16 ----------------
__global__ void k_charconv(const float* ct, const int* word, const float* cw,
                           const float* cb, unsigned short* feat){
    __shared__ __align__(16) float x[8][32][20];   // [tok][ic][t]
    int tok0 = blockIdx.x*8;
    for(int e = threadIdx.x; e < 8*32*20; e += 256){
        int t  = e % 20;
        int ic = (e/20) & 31;
        int tl = e / 640;
        int id = word[(size_t)(tok0+tl)*LW_ + t];
        float v = 0.f;
        if(ic < CHAR_E_ && id != 0) v = ct[(size_t)id*CHAR_E_ + ic];
        x[tl][ic][t] = v;
    }
    __syncthreads();
    int tid = threadIdx.x;
    if(tid < 240){
        int tl = tid/30, oc = tid%30;
        float acc[22];
        #pragma unroll
        for(int q=0;q<22;q++) acc[q] = 0.f;
        for(int ic=0; ic<CHAR_E_; ic++){
            float w0 = cw[(oc*CHAR_E_+ic)*3+0];
            float w1 = cw[(oc*CHAR_E_+ic)*3+1];
            float w2 = cw[(oc*CHAR_E_+ic)*3+2];
            const float* xr = &x[tl][ic][0];
            #pragma unroll
            for(int t4=0;t4<5;t4++){
                float4 v = ((const float4*)xr)[t4];
                int t0 = t4*4;
                acc[t0+2] += v.x*w0; acc[t0+1] += v.x*w1; acc[t0+0] += v.x*w2;
                acc[t0+3] += v.y*w0; acc[t0+2] += v.y*w1; acc[t0+1] += v.y*w2;
                acc[t0+4] += v.z*w0; acc[t0+3] += v.z*w1; acc[t0+2] += v.z*w2;
                acc[t0+5] += v.w*w0; acc[t0+4] += v.w*w1; acc[t0+3] += v.w*w2;
            }
        }
        float m = -1e30f;
        #pragma unroll
        for(int t=0;t<20;t++){ float v = acc[t+1]; m = fmaxf(m, v); }
        m += cb[oc];
        feat[(size_t)(tok0+tl)*KP_ + WORD_E_ + oc] = (unsigned short)f2bf(m);
    }
}

// ---------------- bf16 MFMA GEMM: gx(bf16) = feat(8192x352) . wpack(2048x352)^T + bias ----------------
__global__ __launch_bounds__(256) void k_gemm(const unsigned short* A, const unsigned short* Bw,
                                              const float* bf, const float* br, unsigned short* gxb){
    __shared__ __align__(16) unsigned short As[64][40];
    __shared__ __align__(16) unsigned short Bs[64][40];
    int m0 = blockIdx.x*64, n0 = blockIdx.y*64;
    int tid = threadIdx.x;
    int w = tid>>6, lane = tid&63, q = lane>>4, l16 = lane&15;
    int srow = tid>>2, koff = (tid&3)*8;
    floatx4 acc0={0.f,0.f,0.f,0.f}, acc1=acc0, acc2=acc0, acc3=acc0;
    for(int k0=0; k0<KP_; k0+=32){
        uint4 av = *(const uint4*)(A  + (size_t)(m0+srow)*KP_ + k0 + koff);
        uint4 bv = *(const uint4*)(Bw + (size_t)(n0+srow)*KP_ + k0 + koff);
        __syncthreads();
        *(uint4*)&As[srow][koff] = av;
        *(uint4*)&Bs[srow][koff] = bv;
        __syncthreads();
        short8 af = *(const short8*)&As[w*16+l16][q*8];
        short8 b0 = *(const short8*)&Bs[l16][q*8];
        short8 b1 = *(const short8*)&Bs[16+l16][q*8];
        short8 b2 = *(const short8*)&Bs[32+l16][q*8];
        short8 b3 = *(const short8*)&Bs[48+l16][q*8];
        acc0 = __builtin_amdgcn_mfma_f32_16x16x32_bf16(af, b0, acc0, 0,0,0);
        acc1 = __builtin_amdgcn_mfma_f32_16x16x32_bf16(af, b1, acc1, 0,0,0);
        acc2 = __builtin_amdgcn_mfma_f32_16x16x32_bf16(af, b2, acc2, 0,0,0);
        acc3 = __builtin_amdgcn_mfma_f32_16x16x32_bf16(af, b3, acc3, 0,0,0);
    }
    #pragma unroll
    for(int nt=0; nt<4; nt++){
        floatx4 a = (nt==0)?acc0:(nt==1)?acc1:(nt==2)?acc2:acc3;
        int n = n0 + nt*16 + l16;
        int dirr = n >> 10, grow = n & 1023;
        float bias = dirr ? br[grow] : bf[grow];
        #pragma unroll
        for(int r=0; r<4; r++){
            int m = m0 + w*16 + q*4 + r;
            int b = m >> 7, s = m & 127;
            gxb[(((size_t)dirr*S_ + s)*B_ + b)*G4_ + grow] = (unsigned short)f2bf(a[r] + bias);
        }
    }
}

// ---------------- persistent biLSTM: 32 blocks x 1024 threads ----------------
// block = (dir, 4-batch group). Full-direction w_hh (1024x256) fp8 e4m3 (x64) in
// 64 VGPRs/lane. h (fp8, x16) in LDS. Gates redistributed through padded LDS so
// the cell update runs 1 (unit,batch) pair per thread (all 64 lanes useful).
__global__ __launch_bounds__(1024,1) void k_lstm_all(const float* whhf, const float* whhr,
        const unsigned short* gxb, float* hseq)
{
    int bid = blockIdx.x;        // 0..31
    int dir = bid >> 4;
    int bg  = bid & 15;          // 4 batches: bg*4 .. bg*4+3
    int tid = threadIdx.x;
    int w    = tid >> 6;         // wave 0..15: units w*16..w*16+15
    int lane = tid & 63;
    int q    = lane >> 4;
    int l16  = lane & 15;

    __shared__ __align__(16) unsigned char hlds[16*264];    // B-frag rows: row=batch col=unit; rows 4..15 stay 0
    __shared__ __align__(16) float gbuf[4*256*5];           // [g][u][b] stride-5 pad (20 KB)

    const float* whh = dir ? whhr : whhf;

    // one-time: convert my weight slice to fp8 A-fragments (rows g*256+w*16+l16, k=kt*32+q*8+j)
    long wreg[4][8];
    #pragma unroll
    for(int g=0; g<4; g++){
        const float* rp = whh + (size_t)(g*H_ + w*16 + l16)*H_;
        #pragma unroll
        for(int kt=0; kt<8; kt++){
            const float* p = rp + kt*32 + q*8;
            unsigned int d0 = 0, d1 = 0;
            d0 = __builtin_amdgcn_cvt_pk_fp8_f32(p[0]*64.f, p[1]*64.f, d0, false);
            d0 = __builtin_amdgcn_cvt_pk_fp8_f32(p[2]*64.f, p[3]*64.f, d0, true);
            d1 = __builtin_amdgcn_cvt_pk_fp8_f32(p[4]*64.f, p[5]*64.f, d1, false);
            d1 = __builtin_amdgcn_cvt_pk_fp8_f32(p[6]*64.f, p[7]*64.f, d1, true);
            wreg[g][kt] = (long)(((unsigned long long)d1 << 32) | d0);
        }
    }

    for(int i = tid; i < 16*264/4; i += 1024) ((unsigned int*)hlds)[i] = 0;
    __syncthreads();

    // cell role: one (unit,batch) pair per thread
    int cu  = tid & 255;         // unit
    int cb  = tid >> 8;          // batch 0..3
    int u0  = w*16 + q*4;        // MFMA-role unit base
    const float inv_sc = 1.0f/1024.f;   // w x64, h x16

    float cc = 0.f;              // cell state for my pair
    const unsigned short* gbase = gxb + (size_t)dir*S_*B_*G4_ + (size_t)(bg*4 + cb)*G4_ + cu;

    // prefetch step 0's gate biases (bf16)
    unsigned int gc0, gc1, gc2, gc3, gn0=0, gn1=0, gn2=0, gn3=0;
    {
        const unsigned short* gp = gbase + (size_t)(dir ? (S_-1) : 0)*B_*G4_;
        gc0 = gp[0]; gc1 = gp[256]; gc2 = gp[512]; gc3 = gp[768];
    }

    for(int t=0; t<S_; t++){
        int s = dir ? (S_-1-t) : t;

        // A: prefetch t+1's gate biases (stay in flight across lgkm-only barriers)
        if(t+1 < S_){
            const unsigned short* gp = gbase + (size_t)(dir ? (s-1) : (s+1))*B_*G4_;
            gn0 = gp[0]; gn1 = gp[256]; gn2 = gp[512]; gn3 = gp[768];
        }

        // B: gates = W @ h(t-1)
        floatx4 a0={0.f,0.f,0.f,0.f}, a1=a0, a2=a0, a3=a0;
        #pragma unroll
        for(int kt=0; kt<8; kt++){
            long hb = *(const long*)&hlds[l16*264 + kt*32 + q*8];
            a0 = __builtin_amdgcn_mfma_f32_16x16x32_fp8_fp8(wreg[0][kt], hb, a0, 0,0,0);
            a1 = __builtin_amdgcn_mfma_f32_16x16x32_fp8_fp8(wreg[1][kt], hb, a1, 0,0,0);
            a2 = __builtin_amdgcn_mfma_f32_16x16x32_fp8_fp8(wreg[2][kt], hb, a2, 0,0,0);
            a3 = __builtin_amdgcn_mfma_f32_16x16x32_fp8_fp8(wreg[3][kt], hb, a3, 0,0,0);
        }

        // C: scatter valid gate columns (l16<4) to gbuf
        if(l16 < 4){
            #pragma unroll
            for(int r=0; r<4; r++){
                int u = u0 + r;
                gbuf[(0*256+u)*5 + l16] = a0[r];
                gbuf[(1*256+u)*5 + l16] = a1[r];
                gbuf[(2*256+u)*5 + l16] = a2[r];
                gbuf[(3*256+u)*5 + l16] = a3[r];
            }
        }

        BAR_LDS();   // gbuf ready; all hlds reads of h(t-1) complete

        // E: cell update, 1 pair per thread
        {
            float iv = gbuf[(0*256+cu)*5 + cb]*inv_sc + bf2f(gc0);
            float fv = gbuf[(1*256+cu)*5 + cb]*inv_sc + bf2f(gc1);
            float gv = gbuf[(2*256+cu)*5 + cb]*inv_sc + bf2f(gc2);
            float ov = gbuf[(3*256+cu)*5 + cb]*inv_sc + bf2f(gc3);
            float cn = sigmoidf_(fv)*cc + sigmoidf_(iv)*tanh_(gv);
            cc = cn;
            float hv = sigmoidf_(ov)*tanh_(cn);
            hseq[(((size_t)dir*S_ + s)*B_ + bg*4 + cb)*H_ + cu] = hv;
            unsigned int hp = __builtin_amdgcn_cvt_pk_fp8_f32(hv*16.f, hv*16.f, 0u, false);
            hlds[cb*264 + cu] = (unsigned char)(hp & 0xFF);
        }

        BAR_LDS();   // h(t) visible; gbuf free for next step

        gc0=gn0; gc1=gn1; gc2=gn2; gc3=gn3;
    }
}

// ---------------- emissions: block = 8 (s,b) pairs, h staged in LDS ----------------
__global__ __launch_bounds__(256) void k_em(const float* hseq, const float* lw, const float* lb, float* em){
    __shared__ __align__(16) float hb[8][516];   // +4 pad
    int sb0 = blockIdx.x*8;
    int tid = threadIdx.x;
    for(int i = tid; i < 1024; i += 256){
        int p = i >> 7, r = i & 127;
        int sb = sb0 + p, s = sb >> 6, b = sb & 63;
        const float* src = (r < 64) ? (hseq + (((size_t)0*S_+s)*B_+b)*H_ + r*4)
                                    : (hseq + (((size_t)1*S_+s)*B_+b)*H_ + (r-64)*4);
        *(float4*)&hb[p][r*4] = *(const float4*)src;
    }
    __syncthreads();
    if(tid < 200){
        int p = tid / 25, nc = tid % 25;
        const float4* wv = (const float4*)(lw + (size_t)nc*2*H_);
        const float4* hv = (const float4*)&hb[p][0];
        float acc = lb[nc];
        #pragma unroll 16
        for(int k=0;k<128;k++){ float4 a=hv[k], ww=wv[k]; acc += a.x*ww.x + a.y*ww.y + a.z*ww.z + a.w*ww.w; }
        em[(size_t)(sb0+p)*NC_ + nc] = acc;
    }
}

// ---------------- CRF NLL: one block (64 threads) per batch; out += logZ - score ----------------
__global__ void k_crf(const float* em, const int* tag, const void* mask,
                      const float* st, const float* et, const float* tr, float* out){
    __shared__ float trs[NC_*NC_];
    __shared__ float alpha[2][NC_];
    __shared__ float score_sh;
    __shared__ int   len_sh;
    int b = blockIdx.x, tid = threadIdx.x;
    for(int i=tid;i<NC_*NC_;i+=64) trs[i]=tr[i];
    unsigned int first = *(const unsigned int*)mask;
    int ml;  // 0=int32, 1=uint8, 2=float32
    if(first == 1u) ml = 0;
    else if(first == 0x3F800000u) ml = 2;
    else ml = 1;
    __syncthreads();

    float part = 0.f; int cnt = 0;
    for(int s = tid; s < S_; s += 64){
        float mkv;
        {
            int off = b*S_ + s;
            if(ml==0)      mkv = ((const int*)mask)[off] ? 1.f : 0.f;
            else if(ml==1) mkv = ((const unsigned char*)mask)[off] ? 1.f : 0.f;
            else           mkv = ((const float*)mask)[off];
        }
        cnt += (mkv != 0.f) ? 1 : 0;
        if(s == 0){
            int t0 = tag[b*S_];
            part += st[t0] + em[((size_t)0*B_ + b)*NC_ + t0];
        } else {
            int tp = tag[b*S_ + s-1], tc = tag[b*S_ + s];
            part += mkv * (trs[tp*NC_ + tc] + em[((size_t)s*B_ + b)*NC_ + tc]);
        }
    }
    for(int o=32;o>0;o>>=1){ part += __shfl_down(part, o); cnt += __shfl_down(cnt, o); }
    if(tid==0){ len_sh = cnt; score_sh = part; }
    __syncthreads();
    float score = 0.f;
    if(tid == 0){
        int last = len_sh - 1;
        score = score_sh + et[ tag[b*S_ + last] ];
    }

    if(tid < NC_) alpha[0][tid] = st[tid] + em[((size_t)0*B_ + b)*NC_ + tid];
    __syncthreads();
    int cur = 0;
    for(int s=1;s<S_;s++){
        float nv = 0.f;
        if(tid < NC_){
            int j = tid;
            float m = -1e30f;
            #pragma unroll
            for(int i=0;i<NC_;i++){ float v = alpha[cur][i] + trs[i*NC_+j]; m = fmaxf(m, v); }
            float sum = 0.f;
            #pragma unroll
            for(int i=0;i<NC_;i++){ sum += __expf(alpha[cur][i] + trs[i*NC_+j] - m); }
            float nxt = m + __logf(sum) + em[((size_t)s*B_ + b)*NC_ + j];
            float mkv;
            {
                int off = b*S_ + s;
                if(ml==0)      mkv = ((const int*)mask)[off] ? 1.f : 0.f;
                else if(ml==1) mkv = ((const unsigned char*)mask)[off] ? 1.f : 0.f;
                else           mkv = ((const float*)mask)[off];
            }
            nv = (mkv != 0.f) ? nxt : alpha[cur][j];
        }
        __syncthreads();
        if(tid < NC_) alpha[cur^1][tid] = nv;
        __syncthreads();
        cur ^= 1;
    }
    float v = (tid < NC_) ? (alpha[cur][tid] + et[tid]) : -1e30f;
    float m = v;
    for(int o=32;o>0;o>>=1) m = fmaxf(m, __shfl_down(m, o));
    m = __shfl(m, 0);
    float e = (tid < NC_) ? __expf(v - m) : 0.f;
    for(int o=32;o>0;o>>=1) e += __shfl_down(e, o);
    if(tid == 0){
        float logZ = m + __logf(e);
        atomicAdd(out, logZ - score);
    }
}

extern "C" void kernel_launch(void* const* d_in, const int* in_sizes, int n_in,
                              void* d_out, int out_size, void* d_ws, size_t ws_size,
                              hipStream_t stream) {
    const float* word_table = (const float*)d_in[0];
    const float* char_table = (const float*)d_in[1];
    const float* conv_w     = (const float*)d_in[2];
    const float* conv_b     = (const float*)d_in[3];
    const float* w_ih_f     = (const float*)d_in[4];
    const float* w_hh_f     = (const float*)d_in[5];
    const float* b_f        = (const float*)d_in[6];
    const float* w_ih_r     = (const float*)d_in[7];
    const float* w_hh_r     = (const float*)d_in[8];
    const float* b_r        = (const float*)d_in[9];
    const float* lin_w      = (const float*)d_in[10];
    const float* lin_b      = (const float*)d_in[11];
    const float* start_t    = (const float*)d_in[12];
    const float* end_t      = (const float*)d_in[13];
    const float* trans      = (const float*)d_in[14];
    const int*   sent       = (const int*)d_in[15];
    const int*   word       = (const int*)d_in[16];
    const int*   tag        = (const int*)d_in[17];
    const void*  mask       = d_in[18];
    float* out = (float*)d_out;

    char* ws = (char*)d_ws;
    unsigned short* feat  = (unsigned short*)ws;                 // 8192*352*2   = 5,767,168 B
    unsigned short* wpack = (unsigned short*)(ws + 5767168);     // 2048*352*2   = 1,441,792 B
    unsigned short* gxb   = (unsigned short*)(ws + 5767168 + 1441792);           // 33,554,432 B
    float* hseq = (float*)(ws + 5767168 + 1441792 + 33554432);   // 16,777,216 B
    float* em   = (float*)(ws + 5767168 + 1441792 + 33554432 + 16777216);        // 204,800 f

    k_init<<<dim3(1), 64, 0, stream>>>(out);
    k_pack<<<dim3((NG_*KP_+255)/256), 256, 0, stream>>>(w_ih_f, w_ih_r, wpack);
    k_wemb<<<dim3((B_*S_*76+255)/256), 256, 0, stream>>>(word_table, sent, feat);
    k_charconv<<<dim3(B_*S_/8), 256, 0, stream>>>(char_table, word, conv_w, conv_b, feat);
    k_gemm<<<dim3(B_*S_/64, NG_/64), 256, 0, stream>>>(feat, wpack, b_f, b_r, gxb);
    k_lstm_all<<<dim3(32), 1024, 0, stream>>>(w_hh_f, w_hh_r, gxb, hseq);
    k_em<<<dim3(S_*B_/8), 256, 0, stream>>>(hseq, lin_w, lin_b, em);
    k_crf<<<dim3(B_), 64, 0, stream>>>(em, tag, mask, start_t, end_t, trans, out);
}

// Round 8
// 676.521 us; speedup vs baseline: 1.8035x; 1.0498x over previous
//
#include <hip/hip_runtime.h>
#include <math.h>

#define B_  64
#define S_  128
#define LW_ 20
#define CHAR_E_ 30
#define CHAR_C_ 30
#define WORD_E_ 300
#define H_  256
#define NC_ 25
#define F_  330
#define KP_ 352       // K padded to multiple of 32
#define G4_ 1024      // 4*H
#define NG_ 2048      // both directions' gates

typedef __attribute__((ext_vector_type(8))) short short8;
typedef __attribute__((ext_vector_type(4))) float floatx4;
typedef __attribute__((ext_vector_type(8))) int int8v;

__device__ __forceinline__ float sigmoidf_(float x){ return 1.0f/(1.0f+__expf(-x)); }
__device__ __forceinline__ float tanh_(float x){ return 1.0f - 2.0f/(1.0f+__expf(2.0f*x)); }

__device__ __forceinline__ unsigned int f2bf(float f){
    unsigned int u = __float_as_uint(f);
    u += 0x7FFFu + ((u>>16)&1u);
    return (u>>16) & 0xFFFFu;
}
__device__ __forceinline__ float bf2f(unsigned int v){ return __uint_as_float(v<<16); }

// LDS-only barrier: does NOT drain vmcnt, so global prefetch loads stay in flight.
#define BAR_LDS() __asm__ volatile("s_waitcnt lgkmcnt(0)\n\ts_barrier" ::: "memory")

// ---------------- init: zero output scalar ----------------
__global__ void k_init(float* out){
    if(blockIdx.x==0 && threadIdx.x==0) *out = 0.f;
}

// ---------------- pack w_ih (f then r) into bf16 (2048 x 352), zero-padded ----------------
__global__ void k_pack(const float* wf, const float* wr, unsigned short* wp){
    int i = blockIdx.x*256 + threadIdx.x;
    if(i >= NG_*KP_) return;
    int r = i / KP_, k = i % KP_;
    const float* src = (r < G4_) ? wf : wr;
    int rr = r & (G4_-1);
    wp[i] = (k < F_) ? (unsigned short)f2bf(src[(size_t)rr*F_ + k]) : 0;
}

// ---------------- word embedding gather into feat cols [0,300) bf16, zeros [330,352) ----------------
__global__ void k_wemb(const float* wt, const int* sent, unsigned short* feat){
    int idx = blockIdx.x*256 + threadIdx.x;
    if(idx >= B_*S_*76) return;
    int n = idx / 76, e4 = idx % 76;
    if(e4 < 75){
        float4 v = ((const float4*)(wt + (size_t)sent[n]*WORD_E_))[e4];
        unsigned int lo = f2bf(v.x) | (f2bf(v.y)<<16);
        unsigned int hi = f2bf(v.z) | (f2bf(v.w)<<16);
        uint2 pr; pr.x = lo; pr.y = hi;
        *(uint2*)(feat + (size_t)n*KP_ + e4*4) = pr;
    } else {
        unsigned int* z = (unsigned int*)(feat + (size_t)n*KP_ + 330);
        #pragma unroll
        for(int q=0;q<11;q++) z[q] = 0;
    }
}

// ---------------- char conv + maxpool into feat cols [300,330) bf16 ----------------
__global__ void k_charconv(const float* ct, const int* word, const float* cw,
                           const float* cb, unsigned short* feat){
    __shared__ __align__(16) float x[8][32][20];   // [tok][ic][t]
    int tok0 = blockIdx.x*8;
    for(int e = threadIdx.x; e < 8*32*20; e += 256){
        int t  = e % 20;
        int ic = (e/20) & 31;
        int tl = e / 640;
        int id = word[(size_t)(tok0+tl)*LW_ + t];
        float v = 0.f;
        if(ic < CHAR_E_ && id != 0) v = ct[(size_t)id*CHAR_E_ + ic];
        x[tl][ic][t] = v;
    }
    __syncthreads();
    int tid = threadIdx.x;
    if(tid < 240){
        int tl = tid/30, oc = tid%30;
        float acc[22];
        #pragma unroll
        for(int q=0;q<22;q++) acc[q] = 0.f;
        for(int ic=0; ic<CHAR_E_; ic++){
            float w0 = cw[(oc*CHAR_E_+ic)*3+0];
            float w1 = cw[(oc*CHAR_E_+ic)*3+1];
            float w2 = cw[(oc*CHAR_E_+ic)*3+2];
            const float* xr = &x[tl][ic][0];
            #pragma unroll
            for(int t4=0;t4<5;t4++){
                float4 v = ((const float4*)xr)[t4];
                int t0 = t4*4;
                acc[t0+2] += v.x*w0; acc[t0+1] += v.x*w1; acc[t0+0] += v.x*w2;
                acc[t0+3] += v.y*w0; acc[t0+2] += v.y*w1; acc[t0+1] += v.y*w2;
                acc[t0+4] += v.z*w0; acc[t0+3] += v.z*w1; acc[t0+2] += v.z*w2;
                acc[t0+5] += v.w*w0; acc[t0+4] += v.w*w1; acc[t0+3] += v.w*w2;
            }
        }
        float m = -1e30f;
        #pragma unroll
        for(int t=0;t<20;t++){ float v = acc[t+1]; m = fmaxf(m, v); }
        m += cb[oc];
        feat[(size_t)(tok0+tl)*KP_ + WORD_E_ + oc] = (unsigned short)f2bf(m);
    }
}

// ---------------- bf16 MFMA GEMM: gx(bf16) = feat(8192x352) . wpack(2048x352)^T + bias ----------------
__global__ __launch_bounds__(256) void k_gemm(const unsigned short* A, const unsigned short* Bw,
                                              const float* bf, const float* br, unsigned short* gxb){
    __shared__ __align__(16) unsigned short As[64][40];
    __shared__ __align__(16) unsigned short Bs[64][40];
    int m0 = blockIdx.x*64, n0 = blockIdx.y*64;
    int tid = threadIdx.x;
    int w = tid>>6, lane = tid&63, q = lane>>4, l16 = lane&15;
    int srow = tid>>2, koff = (tid&3)*8;
    floatx4 acc0={0.f,0.f,0.f,0.f}, acc1=acc0, acc2=acc0, acc3=acc0;
    for(int k0=0; k0<KP_; k0+=32){
        uint4 av = *(const uint4*)(A  + (size_t)(m0+srow)*KP_ + k0 + koff);
        uint4 bv = *(const uint4*)(Bw + (size_t)(n0+srow)*KP_ + k0 + koff);
        __syncthreads();
        *(uint4*)&As[srow][koff] = av;
        *(uint4*)&Bs[srow][koff] = bv;
        __syncthreads();
        short8 af = *(const short8*)&As[w*16+l16][q*8];
        short8 b0 = *(const short8*)&Bs[l16][q*8];
        short8 b1 = *(const short8*)&Bs[16+l16][q*8];
        short8 b2 = *(const short8*)&Bs[32+l16][q*8];
        short8 b3 = *(const short8*)&Bs[48+l16][q*8];
        acc0 = __builtin_amdgcn_mfma_f32_16x16x32_bf16(af, b0, acc0, 0,0,0);
        acc1 = __builtin_amdgcn_mfma_f32_16x16x32_bf16(af, b1, acc1, 0,0,0);
        acc2 = __builtin_amdgcn_mfma_f32_16x16x32_bf16(af, b2, acc2, 0,0,0);
        acc3 = __builtin_amdgcn_mfma_f32_16x16x32_bf16(af, b3, acc3, 0,0,0);
    }
    #pragma unroll
    for(int nt=0; nt<4; nt++){
        floatx4 a = (nt==0)?acc0:(nt==1)?acc1:(nt==2)?acc2:acc3;
        int n = n0 + nt*16 + l16;
        int dirr = n >> 10, grow = n & 1023;
        float bias = dirr ? br[grow] : bf[grow];
        #pragma unroll
        for(int r=0; r<4; r++){
            int m = m0 + w*16 + q*4 + r;
            int b = m >> 7, s = m & 127;
            gxb[(((size_t)dirr*S_ + s)*B_ + b)*G4_ + grow] = (unsigned short)f2bf(a[r] + bias);
        }
    }
}

// ---------------- persistent biLSTM: 32 blocks x 1024 threads ----------------
// block = (dir, 4-batch group). Full-direction w_hh (1024x256) fp8 e4m3 (x64) in
// 64 VGPRs/lane as K=128 MX-MFMA A-fragments (scale=1.0). h (fp8, x16) in LDS.
// Gate K-loop: 2 x 4 mfma_scale_f32_16x16x128_f8f6f4 (vs 8 x 4 K=32) -> ~2.2x
// less matrix-pipe occupancy. Gates redistributed via padded LDS; cell update
// 1 (unit,batch) pair per thread. lgkm-only barriers keep gx prefetch in flight.
__global__ __launch_bounds__(1024,1) void k_lstm_all(const float* whhf, const float* whhr,
        const unsigned short* gxb, float* hseq)
{
    int bid = blockIdx.x;        // 0..31
    int dir = bid >> 4;
    int bg  = bid & 15;          // 4 batches: bg*4 .. bg*4+3
    int tid = threadIdx.x;
    int w    = tid >> 6;         // wave 0..15: units w*16..w*16+15
    int lane = tid & 63;
    int q    = lane >> 4;
    int l16  = lane & 15;

    __shared__ __align__(16) unsigned char hlds[16*272];    // row=batch (stride 272: 16B-aligned)
    __shared__ __align__(16) float gbuf[4*256*5];           // [g][u][b] stride-5 pad (20 KB)

    const float* whh = dir ? whhr : whhf;

    // one-time: pack my weight slice as K=128 fp8 A-fragments.
    // k-map (must match B-load): k = ki*128 + q*32 + j, j = byte 0..31 over 8 dwords.
    // A row = l16 -> gate row g*256 + w*16 + l16.
    int8v wreg[4][2];
    #pragma unroll
    for(int g=0; g<4; g++){
        const float* rp = whh + (size_t)(g*H_ + w*16 + l16)*H_;
        #pragma unroll
        for(int ki=0; ki<2; ki++){
            const float* p = rp + ki*128 + q*32;
            int8v acc;
            #pragma unroll
            for(int wd=0; wd<8; wd++){
                unsigned int d = 0;
                d = __builtin_amdgcn_cvt_pk_fp8_f32(p[wd*4+0]*64.f, p[wd*4+1]*64.f, d, false);
                d = __builtin_amdgcn_cvt_pk_fp8_f32(p[wd*4+2]*64.f, p[wd*4+3]*64.f, d, true);
                acc[wd] = (int)d;
            }
            wreg[g][ki] = acc;
        }
    }

    for(int i = tid; i < 16*272/4; i += 1024) ((unsigned int*)hlds)[i] = 0;
    __syncthreads();

    // cell role: one (unit,batch) pair per thread
    int cu  = tid & 255;         // unit
    int cb  = tid >> 8;          // batch 0..3
    int u0  = w*16 + q*4;        // MFMA-role unit base (D rows q*4+r)
    const float inv_sc = 1.0f/1024.f;   // w x64, h x16

    float cc = 0.f;              // cell state for my pair
    const unsigned short* gbase = gxb + (size_t)dir*S_*B_*G4_ + (size_t)(bg*4 + cb)*G4_ + cu;

    // prefetch step 0's gate biases (bf16)
    unsigned int gc0, gc1, gc2, gc3, gn0=0, gn1=0, gn2=0, gn3=0;
    {
        const unsigned short* gp = gbase + (size_t)(dir ? (S_-1) : 0)*B_*G4_;
        gc0 = gp[0]; gc1 = gp[256]; gc2 = gp[512]; gc3 = gp[768];
    }

    for(int t=0; t<S_; t++){
        int s = dir ? (S_-1-t) : t;

        // A: prefetch t+1's gate biases (stay in flight across lgkm-only barriers)
        if(t+1 < S_){
            const unsigned short* gp = gbase + (size_t)(dir ? (s-1) : (s+1))*B_*G4_;
            gn0 = gp[0]; gn1 = gp[256]; gn2 = gp[512]; gn3 = gp[768];
        }

        // B: gates = W @ h(t-1), two K=128 scaled MFMAs per gate
        floatx4 a0={0.f,0.f,0.f,0.f}, a1=a0, a2=a0, a3=a0;
        #pragma unroll
        for(int ki=0; ki<2; ki++){
            int8v hb = *(const int8v*)&hlds[l16*272 + ki*128 + q*32];
            a0 = __builtin_amdgcn_mfma_scale_f32_16x16x128_f8f6f4(wreg[0][ki], hb, a0, 0, 0, 0, 0x7F, 0, 0x7F);
            a1 = __builtin_amdgcn_mfma_scale_f32_16x16x128_f8f6f4(wreg[1][ki], hb, a1, 0, 0, 0, 0x7F, 0, 0x7F);
            a2 = __builtin_amdgcn_mfma_scale_f32_16x16x128_f8f6f4(wreg[2][ki], hb, a2, 0, 0, 0, 0x7F, 0, 0x7F);
            a3 = __builtin_amdgcn_mfma_scale_f32_16x16x128_f8f6f4(wreg[3][ki], hb, a3, 0, 0, 0, 0x7F, 0, 0x7F);
        }

        // C: scatter valid gate columns (l16<4) to gbuf
        if(l16 < 4){
            #pragma unroll
            for(int r=0; r<4; r++){
                int u = u0 + r;
                gbuf[(0*256+u)*5 + l16] = a0[r];
                gbuf[(1*256+u)*5 + l16] = a1[r];
                gbuf[(2*256+u)*5 + l16] = a2[r];
                gbuf[(3*256+u)*5 + l16] = a3[r];
            }
        }

        BAR_LDS();   // gbuf ready; all hlds reads of h(t-1) complete

        // E: cell update, 1 pair per thread
        {
            float iv = gbuf[(0*256+cu)*5 + cb]*inv_sc + bf2f(gc0);
            float fv = gbuf[(1*256+cu)*5 + cb]*inv_sc + bf2f(gc1);
            float gv = gbuf[(2*256+cu)*5 + cb]*inv_sc + bf2f(gc2);
            float ov = gbuf[(3*256+cu)*5 + cb]*inv_sc + bf2f(gc3);
            float cn = sigmoidf_(fv)*cc + sigmoidf_(iv)*tanh_(gv);
            cc = cn;
            float hv = sigmoidf_(ov)*tanh_(cn);
            hseq[(((size_t)dir*S_ + s)*B_ + bg*4 + cb)*H_ + cu] = hv;
            unsigned int hp = __builtin_amdgcn_cvt_pk_fp8_f32(hv*16.f, hv*16.f, 0u, false);
            hlds[cb*272 + cu] = (unsigned char)(hp & 0xFF);
        }

        BAR_LDS();   // h(t) visible; gbuf free for next step

        gc0=gn0; gc1=gn1; gc2=gn2; gc3=gn3;
    }
}

// ---------------- emissions: block = 8 (s,b) pairs, h staged in LDS ----------------
__global__ __launch_bounds__(256) void k_em(const float* hseq, const float* lw, const float* lb, float* em){
    __shared__ __align__(16) float hb[8][516];   // +4 pad
    int sb0 = blockIdx.x*8;
    int tid = threadIdx.x;
    for(int i = tid; i < 1024; i += 256){
        int p = i >> 7, r = i & 127;
        int sb = sb0 + p, s = sb >> 6, b = sb & 63;
        const float* src = (r < 64) ? (hseq + (((size_t)0*S_+s)*B_+b)*H_ + r*4)
                                    : (hseq + (((size_t)1*S_+s)*B_+b)*H_ + (r-64)*4);
        *(float4*)&hb[p][r*4] = *(const float4*)src;
    }
    __syncthreads();
    if(tid < 200){
        int p = tid / 25, nc = tid % 25;
        const float4* wv = (const float4*)(lw + (size_t)nc*2*H_);
        const float4* hv = (const float4*)&hb[p][0];
        float acc = lb[nc];
        #pragma unroll 16
        for(int k=0;k<128;k++){ float4 a=hv[k], ww=wv[k]; acc += a.x*ww.x + a.y*ww.y + a.z*ww.z + a.w*ww.w; }
        em[(size_t)(sb0+p)*NC_ + nc] = acc;
    }
}

// ---------------- CRF NLL: one block (64 threads) per batch; out += logZ - score ----------------
__global__ void k_crf(const float* em, const int* tag, const void* mask,
                      const float* st, const float* et, const float* tr, float* out){
    __shared__ float trs[NC_*NC_];
    __shared__ float alpha[2][NC_];
    __shared__ float score_sh;
    __shared__ int   len_sh;
    int b = blockIdx.x, tid = threadIdx.x;
    for(int i=tid;i<NC_*NC_;i+=64) trs[i]=tr[i];
    unsigned int first = *(const unsigned int*)mask;
    int ml;  // 0=int32, 1=uint8, 2=float32
    if(first == 1u) ml = 0;
    else if(first == 0x3F800000u) ml = 2;
    else ml = 1;
    __syncthreads();

    float part = 0.f; int cnt = 0;
    for(int s = tid; s < S_; s += 64){
        float mkv;
        {
            int off = b*S_ + s;
            if(ml==0)      mkv = ((const int*)mask)[off] ? 1.f : 0.f;
            else if(ml==1) mkv = ((const unsigned char*)mask)[off] ? 1.f : 0.f;
            else           mkv = ((const float*)mask)[off];
        }
        cnt += (mkv != 0.f) ? 1 : 0;
        if(s == 0){
            int t0 = tag[b*S_];
            part += st[t0] + em[((size_t)0*B_ + b)*NC_ + t0];
        } else {
            int tp = tag[b*S_ + s-1], tc = tag[b*S_ + s];
            part += mkv * (trs[tp*NC_ + tc] + em[((size_t)s*B_ + b)*NC_ + tc]);
        }
    }
    for(int o=32;o>0;o>>=1){ part += __shfl_down(part, o); cnt += __shfl_down(cnt, o); }
    if(tid==0){ len_sh = cnt; score_sh = part; }
    __syncthreads();
    float score = 0.f;
    if(tid == 0){
        int last = len_sh - 1;
        score = score_sh + et[ tag[b*S_ + last] ];
    }

    if(tid < NC_) alpha[0][tid] = st[tid] + em[((size_t)0*B_ + b)*NC_ + tid];
    __syncthreads();
    int cur = 0;
    for(int s=1;s<S_;s++){
        float nv = 0.f;
        if(tid < NC_){
            int j = tid;
            float m = -1e30f;
            #pragma unroll
            for(int i=0;i<NC_;i++){ float v = alpha[cur][i] + trs[i*NC_+j]; m = fmaxf(m, v); }
            float sum = 0.f;
            #pragma unroll
            for(int i=0;i<NC_;i++){ sum += __expf(alpha[cur][i] + trs[i*NC_+j] - m); }
            float nxt = m + __logf(sum) + em[((size_t)s*B_ + b)*NC_ + j];
            float mkv;
            {
                int off = b*S_ + s;
                if(ml==0)      mkv = ((const int*)mask)[off] ? 1.f : 0.f;
                else if(ml==1) mkv = ((const unsigned char*)mask)[off] ? 1.f : 0.f;
                else           mkv = ((const float*)mask)[off];
            }
            nv = (mkv != 0.f) ? nxt : alpha[cur][j];
        }
        __syncthreads();
        if(tid < NC_) alpha[cur^1][tid] = nv;
        __syncthreads();
        cur ^= 1;
    }
    float v = (tid < NC_) ? (alpha[cur][tid] + et[tid]) : -1e30f;
    float m = v;
    for(int o=32;o>0;o>>=1) m = fmaxf(m, __shfl_down(m, o));
    m = __shfl(m, 0);
    float e = (tid < NC_) ? __expf(v - m) : 0.f;
    for(int o=32;o>0;o>>=1) e += __shfl_down(e, o);
    if(tid == 0){
        float logZ = m + __logf(e);
        atomicAdd(out, logZ - score);
    }
}

extern "C" void kernel_launch(void* const* d_in, const int* in_sizes, int n_in,
                              void* d_out, int out_size, void* d_ws, size_t ws_size,
                              hipStream_t stream) {
    const float* word_table = (const float*)d_in[0];
    const float* char_table = (const float*)d_in[1];
    const float* conv_w     = (const float*)d_in[2];
    const float* conv_b     = (const float*)d_in[3];
    const float* w_ih_f     = (const float*)d_in[4];
    const float* w_hh_f     = (const float*)d_in[5];
    const float* b_f        = (const float*)d_in[6];
    const float* w_ih_r     = (const float*)d_in[7];
    const float* w_hh_r     = (const float*)d_in[8];
    const float* b_r        = (const float*)d_in[9];
    const float* lin_w      = (const float*)d_in[10];
    const float* lin_b      = (const float*)d_in[11];
    const float* start_t    = (const float*)d_in[12];
    const float* end_t      = (const float*)d_in[13];
    const float* trans      = (const float*)d_in[14];
    const int*   sent       = (const int*)d_in[15];
    const int*   word       = (const int*)d_in[16];
    const int*   tag        = (const int*)d_in[17];
    const void*  mask       = d_in[18];
    float* out = (float*)d_out;

    char* ws = (char*)d_ws;
    unsigned short* feat  = (unsigned short*)ws;                 // 8192*352*2   = 5,767,168 B
    unsigned short* wpack = (unsigned short*)(ws + 5767168);     // 2048*352*2   = 1,441,792 B
    unsigned short* gxb   = (unsigned short*)(ws + 5767168 + 1441792);           // 33,554,432 B
    float* hseq = (float*)(ws + 5767168 + 1441792 + 33554432);   // 16,777,216 B
    float* em   = (float*)(ws + 5767168 + 1441792 + 33554432 + 16777216);        // 204,800 f

    k_init<<<dim3(1), 64, 0, stream>>>(out);
    k_pack<<<dim3((NG_*KP_+255)/256), 256, 0, stream>>>(w_ih_f, w_ih_r, wpack);
    k_wemb<<<dim3((B_*S_*76+255)/256), 256, 0, stream>>>(word_table, sent, feat);
    k_charconv<<<dim3(B_*S_/8), 256, 0, stream>>>(char_table, word, conv_w, conv_b, feat);
    k_gemm<<<dim3(B_*S_/64, NG_/64), 256, 0, stream>>>(feat, wpack, b_f, b_r, gxb);
    k_lstm_all<<<dim3(32), 1024, 0, stream>>>(w_hh_f, w_hh_r, gxb, hseq);
    k_em<<<dim3(S_*B_/8), 256, 0, stream>>>(hseq, lin_w, lin_b, em);
    k_crf<<<dim3(B_), 64, 0, stream>>>(em, tag, mask, start_t, end_t, trans, out);
}

// Round 9
// 627.674 us; speedup vs baseline: 1.9438x; 1.0778x over previous
//
#include <hip/hip_runtime.h>
#include <math.h>

#define B_  64
#define S_  128
#define LW_ 20
#define CHAR_E_ 30
#define CHAR_C_ 30
#define WORD_E_ 300
#define H_  256
#define NC_ 25
#define F_  330
#define KP_ 352       // K padded to multiple of 32
#define G4_ 1024      // 4*H
#define NG_ 2048      // both directions' gates

typedef __attribute__((ext_vector_type(8))) short short8;
typedef __attribute__((ext_vector_type(4))) float floatx4;
typedef __attribute__((ext_vector_type(8))) int int8v;

__device__ __forceinline__ float sigmoidf_(float x){ return 1.0f/(1.0f+__expf(-x)); }
__device__ __forceinline__ float tanh_(float x){ return 1.0f - 2.0f/(1.0f+__expf(2.0f*x)); }

__device__ __forceinline__ unsigned int f2bf(float f){
    unsigned int u = __float_as_uint(f);
    u += 0x7FFFu + ((u>>16)&1u);
    return (u>>16) & 0xFFFFu;
}
__device__ __forceinline__ float bf2f(unsigned int v){ return __uint_as_float(v<<16); }

// LDS-only barrier: does NOT drain vmcnt, so global prefetch loads stay in flight.
#define BAR_LDS() __asm__ volatile("s_waitcnt lgkmcnt(0)\n\ts_barrier" ::: "memory")

// ---------------- merged prep: charconv | wemb | pack | init ----------------
// grid = 1024 + 2432 + 2816 + 1 = 6273 blocks x 256
__global__ __launch_bounds__(256) void k_prep(const float* ct, const int* word,
        const float* cw, const float* cb, const float* wt, const int* sent,
        const float* wf, const float* wr, float* out,
        unsigned short* feat, unsigned short* wpack){
    __shared__ __align__(16) float x[8][32][20];
    int blk = blockIdx.x;
    int tid = threadIdx.x;
    if(blk < 1024){
        // -------- char conv + maxpool into feat cols [300,330) --------
        int tok0 = blk*8;
        for(int e = tid; e < 8*32*20; e += 256){
            int t  = e % 20;
            int ic = (e/20) & 31;
            int tl = e / 640;
            int id = word[(size_t)(tok0+tl)*LW_ + t];
            float v = 0.f;
            if(ic < CHAR_E_ && id != 0) v = ct[(size_t)id*CHAR_E_ + ic];
            x[tl][ic][t] = v;
        }
        __syncthreads();
        if(tid < 240){
            int tl = tid/30, oc = tid%30;
            float acc[22];
            #pragma unroll
            for(int q=0;q<22;q++) acc[q] = 0.f;
            for(int ic=0; ic<CHAR_E_; ic++){
                float w0 = cw[(oc*CHAR_E_+ic)*3+0];
                float w1 = cw[(oc*CHAR_E_+ic)*3+1];
                float w2 = cw[(oc*CHAR_E_+ic)*3+2];
                const float* xr = &x[tl][ic][0];
                #pragma unroll
                for(int t4=0;t4<5;t4++){
                    float4 v = ((const float4*)xr)[t4];
                    int t0 = t4*4;
                    acc[t0+2] += v.x*w0; acc[t0+1] += v.x*w1; acc[t0+0] += v.x*w2;
                    acc[t0+3] += v.y*w0; acc[t0+2] += v.y*w1; acc[t0+1] += v.y*w2;
                    acc[t0+4] += v.z*w0; acc[t0+3] += v.z*w1; acc[t0+2] += v.z*w2;
                    acc[t0+5] += v.w*w0; acc[t0+4] += v.w*w1; acc[t0+3] += v.w*w2;
                }
            }
            float m = -1e30f;
            #pragma unroll
            for(int t=0;t<20;t++){ float v = acc[t+1]; m = fmaxf(m, v); }
            m += cb[oc];
            feat[(size_t)(tok0+tl)*KP_ + WORD_E_ + oc] = (unsigned short)f2bf(m);
        }
    } else if(blk < 1024+2432){
        // -------- word embedding into feat cols [0,300), zeros [330,352) --------
        int idx = (blk-1024)*256 + tid;
        int n = idx / 76, e4 = idx % 76;
        if(e4 < 75){
            float4 v = ((const float4*)(wt + (size_t)sent[n]*WORD_E_))[e4];
            unsigned int lo = f2bf(v.x) | (f2bf(v.y)<<16);
            unsigned int hi = f2bf(v.z) | (f2bf(v.w)<<16);
            uint2 pr; pr.x = lo; pr.y = hi;
            *(uint2*)(feat + (size_t)n*KP_ + e4*4) = pr;
        } else {
            unsigned int* z = (unsigned int*)(feat + (size_t)n*KP_ + 330);
            #pragma unroll
            for(int q=0;q<11;q++) z[q] = 0;
        }
    } else if(blk < 6272){
        // -------- pack w_ih (f then r) into bf16 (2048 x 352) --------
        int i = (blk-3456)*256 + tid;
        int r = i / KP_, k = i % KP_;
        const float* src = (r < G4_) ? wf : wr;
        int rr = r & (G4_-1);
        wpack[i] = (k < F_) ? (unsigned short)f2bf(src[(size_t)rr*F_ + k]) : 0;
    } else {
        if(tid == 0) *out = 0.f;
    }
}

// ---------------- bf16 MFMA GEMM: gx(bf16) = feat(8192x352) . wpack(2048x352)^T + bias ----------------
__global__ __launch_bounds__(256) void k_gemm(const unsigned short* A, const unsigned short* Bw,
                                              const float* bf, const float* br, unsigned short* gxb){
    __shared__ __align__(16) unsigned short As[64][40];
    __shared__ __align__(16) unsigned short Bs[64][40];
    int m0 = blockIdx.x*64, n0 = blockIdx.y*64;
    int tid = threadIdx.x;
    int w = tid>>6, lane = tid&63, q = lane>>4, l16 = lane&15;
    int srow = tid>>2, koff = (tid&3)*8;
    floatx4 acc0={0.f,0.f,0.f,0.f}, acc1=acc0, acc2=acc0, acc3=acc0;
    for(int k0=0; k0<KP_; k0+=32){
        uint4 av = *(const uint4*)(A  + (size_t)(m0+srow)*KP_ + k0 + koff);
        uint4 bv = *(const uint4*)(Bw + (size_t)(n0+srow)*KP_ + k0 + koff);
        __syncthreads();
        *(uint4*)&As[srow][koff] = av;
        *(uint4*)&Bs[srow][koff] = bv;
        __syncthreads();
        short8 af = *(const short8*)&As[w*16+l16][q*8];
        short8 b0 = *(const short8*)&Bs[l16][q*8];
        short8 b1 = *(const short8*)&Bs[16+l16][q*8];
        short8 b2 = *(const short8*)&Bs[32+l16][q*8];
        short8 b3 = *(const short8*)&Bs[48+l16][q*8];
        acc0 = __builtin_amdgcn_mfma_f32_16x16x32_bf16(af, b0, acc0, 0,0,0);
        acc1 = __builtin_amdgcn_mfma_f32_16x16x32_bf16(af, b1, acc1, 0,0,0);
        acc2 = __builtin_amdgcn_mfma_f32_16x16x32_bf16(af, b2, acc2, 0,0,0);
        acc3 = __builtin_amdgcn_mfma_f32_16x16x32_bf16(af, b3, acc3, 0,0,0);
    }
    #pragma unroll
    for(int nt=0; nt<4; nt++){
        floatx4 a = (nt==0)?acc0:(nt==1)?acc1:(nt==2)?acc2:acc3;
        int n = n0 + nt*16 + l16;
        int dirr = n >> 10, grow = n & 1023;
        float bias = dirr ? br[grow] : bf[grow];
        #pragma unroll
        for(int r=0; r<4; r++){
            int m = m0 + w*16 + q*4 + r;
            int b = m >> 7, s = m & 127;
            gxb[(((size_t)dirr*S_ + s)*B_ + b)*G4_ + grow] = (unsigned short)f2bf(a[r] + bias);
        }
    }
}

// ---------------- persistent biLSTM: 32 blocks x 1024 threads, ONE barrier/step ----------------
// block = (dir, 4-batch group). w_hh fp8 (x64) as K=128 MX A-frags in 64 VGPRs/lane.
// Wave w owns all 4 gates of units w*16..w*16+15 -> gate->cell redistribution is
// INTRA-wave (private LDS region, lgkm-ordered, no barrier). h double-buffered in
// LDS (fp8, x16) -> single lgkm-only barrier per step; MFMA/VALU co-issue across waves.
__global__ __launch_bounds__(1024,1) void k_lstm_all(const float* whhf, const float* whhr,
        const unsigned short* gxb, float* hseq)
{
    int bid = blockIdx.x;        // 0..31
    int dir = bid >> 4;
    int bg  = bid & 15;          // 4 batches: bg*4 .. bg*4+3
    int tid = threadIdx.x;
    int w    = tid >> 6;         // wave 0..15: units w*16..w*16+15
    int lane = tid & 63;
    int q    = lane >> 4;
    int l16  = lane & 15;

    __shared__ __align__(16) unsigned char hlds[2][16*272];   // [buf][batchrow][unit] fp8
    __shared__ __align__(16) float wregion[16*256];           // per-wave gate xfer (16KB)

    const float* whh = dir ? whhr : whhf;

    // one-time: pack my weight slice as K=128 fp8 A-fragments.
    // k-map (matches B-load): k = ki*128 + q*32 + j. A row = l16 -> gate row g*256+w*16+l16.
    int8v wreg[4][2];
    #pragma unroll
    for(int g=0; g<4; g++){
        const float* rp = whh + (size_t)(g*H_ + w*16 + l16)*H_;
        #pragma unroll
        for(int ki=0; ki<2; ki++){
            const float* p = rp + ki*128 + q*32;
            int8v acc;
            #pragma unroll
            for(int wd=0; wd<8; wd++){
                unsigned int d = 0;
                d = __builtin_amdgcn_cvt_pk_fp8_f32(p[wd*4+0]*64.f, p[wd*4+1]*64.f, d, false);
                d = __builtin_amdgcn_cvt_pk_fp8_f32(p[wd*4+2]*64.f, p[wd*4+3]*64.f, d, true);
                acc[wd] = (int)d;
            }
            wreg[g][ki] = acc;
        }
    }

    for(int i = tid; i < 2*16*272/4; i += 1024) ((unsigned int*)hlds)[i] = 0;
    __syncthreads();

    // cell role (intra-wave): lane = (cbl, urel); unit cu = w*16+urel, batch bg*4+cbl
    int urel = lane & 15;
    int cbl  = lane >> 4;
    int cu   = w*16 + urel;
    int b_glob = bg*4 + cbl;
    const float inv_sc = 1.0f/1024.f;   // w x64, h x16

    float cc = 0.f;
    const unsigned short* gbase = gxb + (size_t)dir*S_*B_*G4_ + (size_t)b_glob*G4_ + cu;

    unsigned int gc0, gc1, gc2, gc3, gn0=0, gn1=0, gn2=0, gn3=0;
    {
        const unsigned short* gp = gbase + (size_t)(dir ? (S_-1) : 0)*B_*G4_;
        gc0 = gp[0]; gc1 = gp[256]; gc2 = gp[512]; gc3 = gp[768];
    }

    float* wreg_lds = &wregion[w*256];

    for(int t=0; t<S_; t++){
        int s = dir ? (S_-1-t) : t;

        // prefetch t+1's gate biases (in flight across the lgkm-only barrier)
        if(t+1 < S_){
            const unsigned short* gp = gbase + (size_t)(dir ? (s-1) : (s+1))*B_*G4_;
            gn0 = gp[0]; gn1 = gp[256]; gn2 = gp[512]; gn3 = gp[768];
        }

        // gates = W @ h(t-1) from buffer t&1
        const unsigned char* hb_base = &hlds[t&1][0];
        floatx4 a0={0.f,0.f,0.f,0.f}, a1=a0, a2=a0, a3=a0;
        #pragma unroll
        for(int ki=0; ki<2; ki++){
            int8v hb = *(const int8v*)&hb_base[l16*272 + ki*128 + q*32];
            a0 = __builtin_amdgcn_mfma_scale_f32_16x16x128_f8f6f4(wreg[0][ki], hb, a0, 0, 0, 0, 0x7F, 0, 0x7F);
            a1 = __builtin_amdgcn_mfma_scale_f32_16x16x128_f8f6f4(wreg[1][ki], hb, a1, 0, 0, 0, 0x7F, 0, 0x7F);
            a2 = __builtin_amdgcn_mfma_scale_f32_16x16x128_f8f6f4(wreg[2][ki], hb, a2, 0, 0, 0, 0x7F, 0, 0x7F);
            a3 = __builtin_amdgcn_mfma_scale_f32_16x16x128_f8f6f4(wreg[3][ki], hb, a3, 0, 0, 0, 0x7F, 0, 0x7F);
        }

        // intra-wave scatter: D col=l16 (batch), row=q*4+r (unit rel). valid cols l16<4.
        if(l16 < 4){
            #pragma unroll
            for(int r=0; r<4; r++){
                int ur = q*4 + r;
                wreg_lds[0*64 + ur*4 + l16] = a0[r];
                wreg_lds[1*64 + ur*4 + l16] = a1[r];
                wreg_lds[2*64 + ur*4 + l16] = a2[r];
                wreg_lds[3*64 + ur*4 + l16] = a3[r];
            }
        }
        // same-wave ds write->read: ordered by lgkmcnt, no barrier
        float iv = wreg_lds[0*64 + urel*4 + cbl]*inv_sc + bf2f(gc0);
        float fv = wreg_lds[1*64 + urel*4 + cbl]*inv_sc + bf2f(gc1);
        float gv = wreg_lds[2*64 + urel*4 + cbl]*inv_sc + bf2f(gc2);
        float ov = wreg_lds[3*64 + urel*4 + cbl]*inv_sc + bf2f(gc3);
        float cn = sigmoidf_(fv)*cc + sigmoidf_(iv)*tanh_(gv);
        cc = cn;
        float hv = sigmoidf_(ov)*tanh_(cn);
        hseq[(((size_t)dir*S_ + s)*B_ + b_glob)*H_ + cu] = hv;
        unsigned int hp = __builtin_amdgcn_cvt_pk_fp8_f32(hv*16.f, hv*16.f, 0u, false);
        hlds[(t&1)^1][cbl*272 + cu] = (unsigned char)(hp & 0xFF);

        BAR_LDS();   // h(t) published; everyone past their reads of buf t&1

        gc0=gn0; gc1=gn1; gc2=gn2; gc3=gn3;
    }
}

// ---------------- emissions: block = 8 (s,b) pairs, h staged in LDS ----------------
__global__ __launch_bounds__(256) void k_em(const float* hseq, const float* lw, const float* lb, float* em){
    __shared__ __align__(16) float hb[8][516];   // +4 pad
    int sb0 = blockIdx.x*8;
    int tid = threadIdx.x;
    for(int i = tid; i < 1024; i += 256){
        int p = i >> 7, r = i & 127;
        int sb = sb0 + p, s = sb >> 6, b = sb & 63;
        const float* src = (r < 64) ? (hseq + (((size_t)0*S_+s)*B_+b)*H_ + r*4)
                                    : (hseq + (((size_t)1*S_+s)*B_+b)*H_ + (r-64)*4);
        *(float4*)&hb[p][r*4] = *(const float4*)src;
    }
    __syncthreads();
    if(tid < 200){
        int p = tid / 25, nc = tid % 25;
        const float4* wv = (const float4*)(lw + (size_t)nc*2*H_);
        const float4* hv = (const float4*)&hb[p][0];
        float acc = lb[nc];
        #pragma unroll 16
        for(int k=0;k<128;k++){ float4 a=hv[k], ww=wv[k]; acc += a.x*ww.x + a.y*ww.y + a.z*ww.z + a.w*ww.w; }
        em[(size_t)(sb0+p)*NC_ + nc] = acc;
    }
}

// ---------------- CRF NLL: one block = one WAVE (64 threads) per batch, no barriers ----------------
// Forward scan via exp-factorization: logsumexp_i(alpha_i+tr_ij) = m + log(sum_i e^{alpha_i-m} E_ij),
// E = exp(tr) held in 25 VGPRs per lane; alpha broadcast via shfl/readlane.
__global__ void k_crf(const float* em, const int* tag, const void* mask,
                      const float* st, const float* et, const float* tr, float* out){
    __shared__ float trs[NC_*NC_];
    int b = blockIdx.x, tid = threadIdx.x;
    for(int i=tid;i<NC_*NC_;i+=64) trs[i]=tr[i];
    unsigned int first = *(const unsigned int*)mask;
    int ml;  // 0=int32, 1=uint8, 2=float32
    if(first == 1u) ml = 0;
    else if(first == 0x3F800000u) ml = 2;
    else ml = 1;
    __syncthreads();

    // gold path score
    float part = 0.f; int cnt = 0;
    for(int s = tid; s < S_; s += 64){
        float mkv;
        {
            int off = b*S_ + s;
            if(ml==0)      mkv = ((const int*)mask)[off] ? 1.f : 0.f;
            else if(ml==1) mkv = ((const unsigned char*)mask)[off] ? 1.f : 0.f;
            else           mkv = ((const float*)mask)[off];
        }
        cnt += (mkv != 0.f) ? 1 : 0;
        if(s == 0){
            int t0 = tag[b*S_];
            part += st[t0] + em[((size_t)0*B_ + b)*NC_ + t0];
        } else {
            int tp = tag[b*S_ + s-1], tc = tag[b*S_ + s];
            part += mkv * (trs[tp*NC_ + tc] + em[((size_t)s*B_ + b)*NC_ + tc]);
        }
    }
    for(int o=32;o>0;o>>=1){ part += __shfl_down(part, o); cnt += __shfl_down(cnt, o); }
    float score = 0.f;
    int len = __shfl(cnt, 0);
    float score0 = __shfl(part, 0);
    if(tid == 0) score = score0 + et[ tag[b*S_ + len-1] ];

    // E columns in registers
    float Ecol[NC_];
    if(tid < NC_){
        #pragma unroll
        for(int i=0;i<NC_;i++) Ecol[i] = __expf(trs[i*NC_+tid]);
    } else {
        #pragma unroll
        for(int i=0;i<NC_;i++) Ecol[i] = 0.f;
    }

    float alpha = (tid < NC_) ? (st[tid] + em[((size_t)0*B_ + b)*NC_ + tid]) : -1e30f;
    float em_n = (tid < NC_) ? em[((size_t)1*B_ + b)*NC_ + tid] : 0.f;

    for(int s=1;s<S_;s++){
        float em_c = em_n;
        if(s+1 < S_) em_n = (tid < NC_) ? em[((size_t)(s+1)*B_ + b)*NC_ + tid] : 0.f;
        float mkv;
        {
            int off = b*S_ + s;
            if(ml==0)      mkv = ((const int*)mask)[off] ? 1.f : 0.f;
            else if(ml==1) mkv = ((const unsigned char*)mask)[off] ? 1.f : 0.f;
            else           mkv = ((const float*)mask)[off];
        }
        // m = max over valid lanes
        float v = alpha;
        for(int o=32;o>0;o>>=1) v = fmaxf(v, __shfl_down(v, o));
        float m = __shfl(v, 0);
        float a = (tid < NC_) ? __expf(alpha - m) : 0.f;
        float S = 0.f;
        #pragma unroll
        for(int i=0;i<NC_;i++){ S += __shfl(a, i) * Ecol[i]; }
        float nxt = m + __logf(S) + em_c;
        if(tid < NC_ && mkv != 0.f) alpha = nxt;
    }

    float v = (tid < NC_) ? (alpha + et[tid]) : -1e30f;
    float m2 = v;
    for(int o=32;o>0;o>>=1) m2 = fmaxf(m2, __shfl_down(m2, o));
    m2 = __shfl(m2, 0);
    float e = (tid < NC_) ? __expf(v - m2) : 0.f;
    for(int o=32;o>0;o>>=1) e += __shfl_down(e, o);
    if(tid == 0){
        float logZ = m2 + __logf(e);
        atomicAdd(out, logZ - score);
    }
}

extern "C" void kernel_launch(void* const* d_in, const int* in_sizes, int n_in,
                              void* d_out, int out_size, void* d_ws, size_t ws_size,
                              hipStream_t stream) {
    const float* word_table = (const float*)d_in[0];
    const float* char_table = (const float*)d_in[1];
    const float* conv_w     = (const float*)d_in[2];
    const float* conv_b     = (const float*)d_in[3];
    const float* w_ih_f     = (const float*)d_in[4];
    const float* w_hh_f     = (const float*)d_in[5];
    const float* b_f        = (const float*)d_in[6];
    const float* w_ih_r     = (const float*)d_in[7];
    const float* w_hh_r     = (const float*)d_in[8];
    const float* b_r        = (const float*)d_in[9];
    const float* lin_w      = (const float*)d_in[10];
    const float* lin_b      = (const float*)d_in[11];
    const float* start_t    = (const float*)d_in[12];
    const float* end_t      = (const float*)d_in[13];
    const float* trans      = (const float*)d_in[14];
    const int*   sent       = (const int*)d_in[15];
    const int*   word       = (const int*)d_in[16];
    const int*   tag        = (const int*)d_in[17];
    const void*  mask       = d_in[18];
    float* out = (float*)d_out;

    char* ws = (char*)d_ws;
    unsigned short* feat  = (unsigned short*)ws;                 // 8192*352*2   = 5,767,168 B
    unsigned short* wpack = (unsigned short*)(ws + 5767168);     // 2048*352*2   = 1,441,792 B
    unsigned short* gxb   = (unsigned short*)(ws + 5767168 + 1441792);           // 33,554,432 B
    float* hseq = (float*)(ws + 5767168 + 1441792 + 33554432);   // 16,777,216 B
    float* em   = (float*)(ws + 5767168 + 1441792 + 33554432 + 16777216);        // 204,800 f

    k_prep<<<dim3(6273), 256, 0, stream>>>(char_table, word, conv_w, conv_b,
                                           word_table, sent, w_ih_f, w_ih_r, out, feat, wpack);
    k_gemm<<<dim3(B_*S_/64, NG_/64), 256, 0, stream>>>(feat, wpack, b_f, b_r, gxb);
    k_lstm_all<<<dim3(32), 1024, 0, stream>>>(w_hh_f, w_hh_r, gxb, hseq);
    k_em<<<dim3(S_*B_/8), 256, 0, stream>>>(hseq, lin_w, lin_b, em);
    k_crf<<<dim3(B_), 64, 0, stream>>>(em, tag, mask, start_t, end_t, trans, out);
}

// Round 10
// 595.931 us; speedup vs baseline: 2.0474x; 1.0533x over previous
//
#include <hip/hip_runtime.h>
#include <math.h>

#define B_  64
#define S_  128
#define LW_ 20
#define CHAR_E_ 30
#define CHAR_C_ 30
#define WORD_E_ 300
#define H_  256
#define NC_ 25
#define F_  330
#define KP_ 352       // K padded to multiple of 32
#define G4_ 1024      // 4*H
#define NG_ 2048      // both directions' gates

typedef __attribute__((ext_vector_type(8))) short short8;
typedef __attribute__((ext_vector_type(4))) float floatx4;
typedef __attribute__((ext_vector_type(8))) int int8v;

__device__ __forceinline__ float sigmoidf_(float x){ return 1.0f/(1.0f+__expf(-x)); }
__device__ __forceinline__ float tanh_(float x){ return 1.0f - 2.0f/(1.0f+__expf(2.0f*x)); }

__device__ __forceinline__ unsigned int f2bf(float f){
    unsigned int u = __float_as_uint(f);
    u += 0x7FFFu + ((u>>16)&1u);
    return (u>>16) & 0xFFFFu;
}
__device__ __forceinline__ float bf2f(unsigned int v){ return __uint_as_float(v<<16); }

// LDS-only barrier: does NOT drain vmcnt, so global prefetch loads stay in flight.
#define BAR_LDS() __asm__ volatile("s_waitcnt lgkmcnt(0)\n\ts_barrier" ::: "memory")

// ---------------- merged prep: charconv | wemb | pack | init ----------------
// grid = 1024 + 2432 + 2816 + 1 = 6273 blocks x 256
__global__ __launch_bounds__(256) void k_prep(const float* ct, const int* word,
        const float* cw, const float* cb, const float* wt, const int* sent,
        const float* wf, const float* wr, float* out,
        unsigned short* feat, unsigned short* wpack){
    __shared__ __align__(16) float x[8][32][20];
    int blk = blockIdx.x;
    int tid = threadIdx.x;
    if(blk < 1024){
        // -------- char conv + maxpool into feat cols [300,330) --------
        int tok0 = blk*8;
        for(int e = tid; e < 8*32*20; e += 256){
            int t  = e % 20;
            int ic = (e/20) & 31;
            int tl = e / 640;
            int id = word[(size_t)(tok0+tl)*LW_ + t];
            float v = 0.f;
            if(ic < CHAR_E_ && id != 0) v = ct[(size_t)id*CHAR_E_ + ic];
            x[tl][ic][t] = v;
        }
        __syncthreads();
        if(tid < 240){
            int tl = tid/30, oc = tid%30;
            float acc[22];
            #pragma unroll
            for(int q=0;q<22;q++) acc[q] = 0.f;
            for(int ic=0; ic<CHAR_E_; ic++){
                float w0 = cw[(oc*CHAR_E_+ic)*3+0];
                float w1 = cw[(oc*CHAR_E_+ic)*3+1];
                float w2 = cw[(oc*CHAR_E_+ic)*3+2];
                const float* xr = &x[tl][ic][0];
                #pragma unroll
                for(int t4=0;t4<5;t4++){
                    float4 v = ((const float4*)xr)[t4];
                    int t0 = t4*4;
                    acc[t0+2] += v.x*w0; acc[t0+1] += v.x*w1; acc[t0+0] += v.x*w2;
                    acc[t0+3] += v.y*w0; acc[t0+2] += v.y*w1; acc[t0+1] += v.y*w2;
                    acc[t0+4] += v.z*w0; acc[t0+3] += v.z*w1; acc[t0+2] += v.z*w2;
                    acc[t0+5] += v.w*w0; acc[t0+4] += v.w*w1; acc[t0+3] += v.w*w2;
                }
            }
            float m = -1e30f;
            #pragma unroll
            for(int t=0;t<20;t++){ float v = acc[t+1]; m = fmaxf(m, v); }
            m += cb[oc];
            feat[(size_t)(tok0+tl)*KP_ + WORD_E_ + oc] = (unsigned short)f2bf(m);
        }
    } else if(blk < 1024+2432){
        // -------- word embedding into feat cols [0,300), zeros [330,352) --------
        int idx = (blk-1024)*256 + tid;
        int n = idx / 76, e4 = idx % 76;
        if(e4 < 75){
            float4 v = ((const float4*)(wt + (size_t)sent[n]*WORD_E_))[e4];
            unsigned int lo = f2bf(v.x) | (f2bf(v.y)<<16);
            unsigned int hi = f2bf(v.z) | (f2bf(v.w)<<16);
            uint2 pr; pr.x = lo; pr.y = hi;
            *(uint2*)(feat + (size_t)n*KP_ + e4*4) = pr;
        } else {
            unsigned int* z = (unsigned int*)(feat + (size_t)n*KP_ + 330);
            #pragma unroll
            for(int q=0;q<11;q++) z[q] = 0;
        }
    } else if(blk < 6272){
        // -------- pack w_ih (f then r) into bf16 (2048 x 352) --------
        int i = (blk-3456)*256 + tid;
        int r = i / KP_, k = i % KP_;
        const float* src = (r < G4_) ? wf : wr;
        int rr = r & (G4_-1);
        wpack[i] = (k < F_) ? (unsigned short)f2bf(src[(size_t)rr*F_ + k]) : 0;
    } else {
        if(tid == 0) *out = 0.f;
    }
}

// ---------------- bf16 MFMA GEMM: gx(bf16) = feat(8192x352) . wpack(2048x352)^T + bias ----------------
__global__ __launch_bounds__(256) void k_gemm(const unsigned short* A, const unsigned short* Bw,
                                              const float* bf, const float* br, unsigned short* gxb){
    __shared__ __align__(16) unsigned short As[64][40];
    __shared__ __align__(16) unsigned short Bs[64][40];
    int m0 = blockIdx.x*64, n0 = blockIdx.y*64;
    int tid = threadIdx.x;
    int w = tid>>6, lane = tid&63, q = lane>>4, l16 = lane&15;
    int srow = tid>>2, koff = (tid&3)*8;
    floatx4 acc0={0.f,0.f,0.f,0.f}, acc1=acc0, acc2=acc0, acc3=acc0;
    for(int k0=0; k0<KP_; k0+=32){
        uint4 av = *(const uint4*)(A  + (size_t)(m0+srow)*KP_ + k0 + koff);
        uint4 bv = *(const uint4*)(Bw + (size_t)(n0+srow)*KP_ + k0 + koff);
        __syncthreads();
        *(uint4*)&As[srow][koff] = av;
        *(uint4*)&Bs[srow][koff] = bv;
        __syncthreads();
        short8 af = *(const short8*)&As[w*16+l16][q*8];
        short8 b0 = *(const short8*)&Bs[l16][q*8];
        short8 b1 = *(const short8*)&Bs[16+l16][q*8];
        short8 b2 = *(const short8*)&Bs[32+l16][q*8];
        short8 b3 = *(const short8*)&Bs[48+l16][q*8];
        acc0 = __builtin_amdgcn_mfma_f32_16x16x32_bf16(af, b0, acc0, 0,0,0);
        acc1 = __builtin_amdgcn_mfma_f32_16x16x32_bf16(af, b1, acc1, 0,0,0);
        acc2 = __builtin_amdgcn_mfma_f32_16x16x32_bf16(af, b2, acc2, 0,0,0);
        acc3 = __builtin_amdgcn_mfma_f32_16x16x32_bf16(af, b3, acc3, 0,0,0);
    }
    #pragma unroll
    for(int nt=0; nt<4; nt++){
        floatx4 a = (nt==0)?acc0:(nt==1)?acc1:(nt==2)?acc2:acc3;
        int n = n0 + nt*16 + l16;
        int dirr = n >> 10, grow = n & 1023;
        float bias = dirr ? br[grow] : bf[grow];
        #pragma unroll
        for(int r=0; r<4; r++){
            int m = m0 + w*16 + q*4 + r;
            int b = m >> 7, s = m & 127;
            gxb[(((size_t)dirr*S_ + s)*B_ + b)*G4_ + grow] = (unsigned short)f2bf(a[r] + bias);
        }
    }
}

// ---------------- persistent biLSTM: 64 blocks x 512 threads (8 waves), ONE barrier/step ----------------
// block = (dir, 2-batch group). Wave w owns units [w*32, w*32+32): 4 gates x 2 unit-tiles x 2 ki
// K=128 MX fp8 A-frags = 128 VGPR/lane. Cell role: 32 units x 2 batches = 64 lanes, exactly
// one (unit,batch) pair per lane, same wave as producer -> intra-wave LDS xfer, no extra barrier.
// h double-buffered fp8 in LDS; single lgkm-only barrier per step.
__global__ __launch_bounds__(512,2) void k_lstm_all(const float* whhf, const float* whhr,
        const unsigned short* gxb, float* hseq)
{
    int bid = blockIdx.x;        // 0..63
    int dir = bid >> 5;
    int bg  = bid & 31;          // 2 batches: bg*2, bg*2+1
    int tid = threadIdx.x;
    int w    = tid >> 6;         // wave 0..7: units w*32..w*32+31
    int lane = tid & 63;
    int q    = lane >> 4;
    int l16  = lane & 15;

    __shared__ __align__(16) unsigned char hlds[2][16*272];   // [buf][batchrow][unit] fp8 (rows 2..15 = 0)
    __shared__ __align__(16) float wregion[8*256];            // per-wave gate xfer (8KB)

    const float* whh = dir ? whhr : whhf;

    // one-time: pack weight slice as K=128 fp8 A-fragments.
    // row = g*256 + w*32 + j*16 + l16 ; k = ki*128 + q*32 + byte (matches B-load)
    int8v wreg[4][2][2];   // [gate][j][ki] -> 128 VGPRs
    #pragma unroll
    for(int g=0; g<4; g++){
        #pragma unroll
        for(int j=0; j<2; j++){
            const float* rp = whh + (size_t)(g*H_ + w*32 + j*16 + l16)*H_;
            #pragma unroll
            for(int ki=0; ki<2; ki++){
                const float* p = rp + ki*128 + q*32;
                int8v acc;
                #pragma unroll
                for(int wd=0; wd<8; wd++){
                    unsigned int d = 0;
                    d = __builtin_amdgcn_cvt_pk_fp8_f32(p[wd*4+0]*64.f, p[wd*4+1]*64.f, d, false);
                    d = __builtin_amdgcn_cvt_pk_fp8_f32(p[wd*4+2]*64.f, p[wd*4+3]*64.f, d, true);
                    acc[wd] = (int)d;
                }
                wreg[g][j][ki] = acc;
            }
        }
    }

    for(int i = tid; i < 2*16*272/4; i += 512) ((unsigned int*)hlds)[i] = 0;
    __syncthreads();

    // cell role (intra-wave): lane = cbl*32 + urel; unit cu = w*32+urel, batch bg*2+cbl
    int urel = lane & 31;
    int cbl  = lane >> 5;        // 0..1
    int cu   = w*32 + urel;
    int b_glob = bg*2 + cbl;
    const float inv_sc = 1.0f/1024.f;   // w x64, h x16

    float cc = 0.f;
    const unsigned short* gbase = gxb + (size_t)dir*S_*B_*G4_ + (size_t)b_glob*G4_ + cu;

    unsigned int gc0, gc1, gc2, gc3, gn0=0, gn1=0, gn2=0, gn3=0;
    {
        const unsigned short* gp = gbase + (size_t)(dir ? (S_-1) : 0)*B_*G4_;
        gc0 = gp[0]; gc1 = gp[256]; gc2 = gp[512]; gc3 = gp[768];
    }

    float* wreg_lds = &wregion[w*256];

    for(int t=0; t<S_; t++){
        int s = dir ? (S_-1-t) : t;

        // prefetch t+1's gate biases (stay in flight across the lgkm-only barrier)
        {
            int sn = dir ? (s>0 ? s-1 : 0) : (s<S_-1 ? s+1 : S_-1);
            const unsigned short* gp = gbase + (size_t)sn*B_*G4_;
            gn0 = gp[0]; gn1 = gp[256]; gn2 = gp[512]; gn3 = gp[768];
        }

        // gates = W @ h(t-1) from buffer t&1
        const unsigned char* hb_base = &hlds[t&1][0];
        floatx4 a[4][2];
        #pragma unroll
        for(int g=0; g<4; g++){ a[g][0] = (floatx4){0.f,0.f,0.f,0.f}; a[g][1] = a[g][0]; }
        #pragma unroll
        for(int ki=0; ki<2; ki++){
            int8v hb = *(const int8v*)&hb_base[l16*272 + ki*128 + q*32];
            #pragma unroll
            for(int g=0; g<4; g++){
                a[g][0] = __builtin_amdgcn_mfma_scale_f32_16x16x128_f8f6f4(wreg[g][0][ki], hb, a[g][0], 0, 0, 0, 0x7F, 0, 0x7F);
                a[g][1] = __builtin_amdgcn_mfma_scale_f32_16x16x128_f8f6f4(wreg[g][1][ki], hb, a[g][1], 0, 0, 0, 0x7F, 0, 0x7F);
            }
        }

        // intra-wave scatter: D col=l16 (batch, valid<2), row=q*4+r -> unit w*32 + j*16 + q*4 + r
        if(l16 < 2){
            #pragma unroll
            for(int g=0; g<4; g++){
                #pragma unroll
                for(int j=0; j<2; j++){
                    #pragma unroll
                    for(int r=0; r<4; r++){
                        wreg_lds[g*64 + (j*16 + q*4 + r)*2 + l16] = a[g][j][r];
                    }
                }
            }
        }
        // same-wave ds write->read: ordered by lgkmcnt, no barrier
        float iv = wreg_lds[0*64 + urel*2 + cbl]*inv_sc + bf2f(gc0);
        float fv = wreg_lds[1*64 + urel*2 + cbl]*inv_sc + bf2f(gc1);
        float gv = wreg_lds[2*64 + urel*2 + cbl]*inv_sc + bf2f(gc2);
        float ov = wreg_lds[3*64 + urel*2 + cbl]*inv_sc + bf2f(gc3);
        float cn = sigmoidf_(fv)*cc + sigmoidf_(iv)*tanh_(gv);
        cc = cn;
        float hv = sigmoidf_(ov)*tanh_(cn);
        hseq[(((size_t)dir*S_ + s)*B_ + b_glob)*H_ + cu] = hv;
        unsigned int hp = __builtin_amdgcn_cvt_pk_fp8_f32(hv*16.f, hv*16.f, 0u, false);
        hlds[(t&1)^1][cbl*272 + cu] = (unsigned char)(hp & 0xFF);

        BAR_LDS();   // h(t) published; everyone past their reads of buf t&1

        gc0=gn0; gc1=gn1; gc2=gn2; gc3=gn3;
    }
}

// ---------------- emissions: block = 8 (s,b) pairs, h staged in LDS ----------------
__global__ __launch_bounds__(256) void k_em(const float* hseq, const float* lw, const float* lb, float* em){
    __shared__ __align__(16) float hb[8][516];   // +4 pad
    int sb0 = blockIdx.x*8;
    int tid = threadIdx.x;
    for(int i = tid; i < 1024; i += 256){
        int p = i >> 7, r = i & 127;
        int sb = sb0 + p, s = sb >> 6, b = sb & 63;
        const float* src = (r < 64) ? (hseq + (((size_t)0*S_+s)*B_+b)*H_ + r*4)
                                    : (hseq + (((size_t)1*S_+s)*B_+b)*H_ + (r-64)*4);
        *(float4*)&hb[p][r*4] = *(const float4*)src;
    }
    __syncthreads();
    if(tid < 200){
        int p = tid / 25, nc = tid % 25;
        const float4* wv = (const float4*)(lw + (size_t)nc*2*H_);
        const float4* hv = (const float4*)&hb[p][0];
        float acc = lb[nc];
        #pragma unroll 16
        for(int k=0;k<128;k++){ float4 a=hv[k], ww=wv[k]; acc += a.x*ww.x + a.y*ww.y + a.z*ww.z + a.w*ww.w; }
        em[(size_t)(sb0+p)*NC_ + nc] = acc;
    }
}

// ---------------- CRF NLL: one block = one WAVE (64 threads) per batch, no barriers ----------------
__global__ void k_crf(const float* em, const int* tag, const void* mask,
                      const float* st, const float* et, const float* tr, float* out){
    __shared__ float trs[NC_*NC_];
    int b = blockIdx.x, tid = threadIdx.x;
    for(int i=tid;i<NC_*NC_;i+=64) trs[i]=tr[i];
    unsigned int first = *(const unsigned int*)mask;
    int ml;  // 0=int32, 1=uint8, 2=float32
    if(first == 1u) ml = 0;
    else if(first == 0x3F800000u) ml = 2;
    else ml = 1;
    __syncthreads();

    // gold path score
    float part = 0.f; int cnt = 0;
    for(int s = tid; s < S_; s += 64){
        float mkv;
        {
            int off = b*S_ + s;
            if(ml==0)      mkv = ((const int*)mask)[off] ? 1.f : 0.f;
            else if(ml==1) mkv = ((const unsigned char*)mask)[off] ? 1.f : 0.f;
            else           mkv = ((const float*)mask)[off];
        }
        cnt += (mkv != 0.f) ? 1 : 0;
        if(s == 0){
            int t0 = tag[b*S_];
            part += st[t0] + em[((size_t)0*B_ + b)*NC_ + t0];
        } else {
            int tp = tag[b*S_ + s-1], tc = tag[b*S_ + s];
            part += mkv * (trs[tp*NC_ + tc] + em[((size_t)s*B_ + b)*NC_ + tc]);
        }
    }
    for(int o=32;o>0;o>>=1){ part += __shfl_down(part, o); cnt += __shfl_down(cnt, o); }
    float score = 0.f;
    int len = __shfl(cnt, 0);
    float score0 = __shfl(part, 0);
    if(tid == 0) score = score0 + et[ tag[b*S_ + len-1] ];

    // E columns in registers
    float Ecol[NC_];
    if(tid < NC_){
        #pragma unroll
        for(int i=0;i<NC_;i++) Ecol[i] = __expf(trs[i*NC_+tid]);
    } else {
        #pragma unroll
        for(int i=0;i<NC_;i++) Ecol[i] = 0.f;
    }

    float alpha = (tid < NC_) ? (st[tid] + em[((size_t)0*B_ + b)*NC_ + tid]) : -1e30f;
    float em_n = (tid < NC_) ? em[((size_t)1*B_ + b)*NC_ + tid] : 0.f;

    for(int s=1;s<S_;s++){
        float em_c = em_n;
        if(s+1 < S_) em_n = (tid < NC_) ? em[((size_t)(s+1)*B_ + b)*NC_ + tid] : 0.f;
        float mkv;
        {
            int off = b*S_ + s;
            if(ml==0)      mkv = ((const int*)mask)[off] ? 1.f : 0.f;
            else if(ml==1) mkv = ((const unsigned char*)mask)[off] ? 1.f : 0.f;
            else           mkv = ((const float*)mask)[off];
        }
        float v = alpha;
        for(int o=32;o>0;o>>=1) v = fmaxf(v, __shfl_down(v, o));
        float m = __shfl(v, 0);
        float a = (tid < NC_) ? __expf(alpha - m) : 0.f;
        float S = 0.f;
        #pragma unroll
        for(int i=0;i<NC_;i++){ S += __shfl(a, i) * Ecol[i]; }
        float nxt = m + __logf(S) + em_c;
        if(tid < NC_ && mkv != 0.f) alpha = nxt;
    }

    float v = (tid < NC_) ? (alpha + et[tid]) : -1e30f;
    float m2 = v;
    for(int o=32;o>0;o>>=1) m2 = fmaxf(m2, __shfl_down(m2, o));
    m2 = __shfl(m2, 0);
    float e = (tid < NC_) ? __expf(v - m2) : 0.f;
    for(int o=32;o>0;o>>=1) e += __shfl_down(e, o);
    if(tid == 0){
        float logZ = m2 + __logf(e);
        atomicAdd(out, logZ - score);
    }
}

extern "C" void kernel_launch(void* const* d_in, const int* in_sizes, int n_in,
                              void* d_out, int out_size, void* d_ws, size_t ws_size,
                              hipStream_t stream) {
    const float* word_table = (const float*)d_in[0];
    const float* char_table = (const float*)d_in[1];
    const float* conv_w     = (const float*)d_in[2];
    const float* conv_b     = (const float*)d_in[3];
    const float* w_ih_f     = (const float*)d_in[4];
    const float* w_hh_f     = (const float*)d_in[5];
    const float* b_f        = (const float*)d_in[6];
    const float* w_ih_r     = (const float*)d_in[7];
    const float* w_hh_r     = (const float*)d_in[8];
    const float* b_r        = (const float*)d_in[9];
    const float* lin_w      = (const float*)d_in[10];
    const float* lin_b      = (const float*)d_in[11];
    const float* start_t    = (const float*)d_in[12];
    const float* end_t      = (const float*)d_in[13];
    const float* trans      = (const float*)d_in[14];
    const int*   sent       = (const int*)d_in[15];
    const int*   word       = (const int*)d_in[16];
    const int*   tag        = (const int*)d_in[17];
    const void*  mask       = d_in[18];
    float* out = (float*)d_out;

    char* ws = (char*)d_ws;
    unsigned short* feat  = (unsigned short*)ws;                 // 8192*352*2   = 5,767,168 B
    unsigned short* wpack = (unsigned short*)(ws + 5767168);     // 2048*352*2   = 1,441,792 B
    unsigned short* gxb   = (unsigned short*)(ws + 5767168 + 1441792);           // 33,554,432 B
    float* hseq = (float*)(ws + 5767168 + 1441792 + 33554432);   // 16,777,216 B
    float* em   = (float*)(ws + 5767168 + 1441792 + 33554432 + 16777216);        // 204,800 f

    k_prep<<<dim3(6273), 256, 0, stream>>>(char_table, word, conv_w, conv_b,
                                           word_table, sent, w_ih_f, w_ih_r, out, feat, wpack);
    k_gemm<<<dim3(B_*S_/64, NG_/64), 256, 0, stream>>>(feat, wpack, b_f, b_r, gxb);
    k_lstm_all<<<dim3(64), 512, 0, stream>>>(w_hh_f, w_hh_r, gxb, hseq);
    k_em<<<dim3(S_*B_/8), 256, 0, stream>>>(hseq, lin_w, lin_b, em);
    k_crf<<<dim3(B_), 64, 0, stream>>>(em, tag, mask, start_t, end_t, trans, out);
}

// Round 11
// 581.315 us; speedup vs baseline: 2.0988x; 1.0251x over previous
//
#include <hip/hip_runtime.h>
#include <math.h>

#define B_  64
#define S_  128
#define LW_ 20
#define CHAR_E_ 30
#define CHAR_C_ 30
#define WORD_E_ 300
#define H_  256
#define NC_ 25
#define F_  330
#define KP_ 352       // K padded to multiple of 32
#define G4_ 1024      // 4*H
#define NG_ 2048      // both directions' gates

typedef __attribute__((ext_vector_type(8))) short short8;
typedef __attribute__((ext_vector_type(4))) float floatx4;
typedef __attribute__((ext_vector_type(8))) int int8v;

__device__ __forceinline__ float sigmoidf_(float x){ return 1.0f/(1.0f+__expf(-x)); }
__device__ __forceinline__ float tanh_(float x){ return 1.0f - 2.0f/(1.0f+__expf(2.0f*x)); }

__device__ __forceinline__ unsigned int f2bf(float f){
    unsigned int u = __float_as_uint(f);
    u += 0x7FFFu + ((u>>16)&1u);
    return (u>>16) & 0xFFFFu;
}
__device__ __forceinline__ float bf2f(unsigned int v){ return __uint_as_float(v<<16); }

// LDS-only barrier: does NOT drain vmcnt, so global prefetch loads stay in flight.
#define BAR_LDS() __asm__ volatile("s_waitcnt lgkmcnt(0)\n\ts_barrier" ::: "memory")

// ---------------- merged prep: charconv | wemb | pack | init ----------------
// grid = 1024 + 2432 + 2816 + 1 = 6273 blocks x 256
__global__ __launch_bounds__(256) void k_prep(const float* ct, const int* word,
        const float* cw, const float* cb, const float* wt, const int* sent,
        const float* wf, const float* wr, float* out,
        unsigned short* feat, unsigned short* wpack){
    __shared__ __align__(16) float x[8][32][20];
    int blk = blockIdx.x;
    int tid = threadIdx.x;
    if(blk < 1024){
        // -------- char conv + maxpool into feat cols [300,330) --------
        int tok0 = blk*8;
        for(int e = tid; e < 8*32*20; e += 256){
            int t  = e % 20;
            int ic = (e/20) & 31;
            int tl = e / 640;
            int id = word[(size_t)(tok0+tl)*LW_ + t];
            float v = 0.f;
            if(ic < CHAR_E_ && id != 0) v = ct[(size_t)id*CHAR_E_ + ic];
            x[tl][ic][t] = v;
        }
        __syncthreads();
        if(tid < 240){
            int tl = tid/30, oc = tid%30;
            float acc[22];
            #pragma unroll
            for(int q=0;q<22;q++) acc[q] = 0.f;
            for(int ic=0; ic<CHAR_E_; ic++){
                float w0 = cw[(oc*CHAR_E_+ic)*3+0];
                float w1 = cw[(oc*CHAR_E_+ic)*3+1];
                float w2 = cw[(oc*CHAR_E_+ic)*3+2];
                const float* xr = &x[tl][ic][0];
                #pragma unroll
                for(int t4=0;t4<5;t4++){
                    float4 v = ((const float4*)xr)[t4];
                    int t0 = t4*4;
                    acc[t0+2] += v.x*w0; acc[t0+1] += v.x*w1; acc[t0+0] += v.x*w2;
                    acc[t0+3] += v.y*w0; acc[t0+2] += v.y*w1; acc[t0+1] += v.y*w2;
                    acc[t0+4] += v.z*w0; acc[t0+3] += v.z*w1; acc[t0+2] += v.z*w2;
                    acc[t0+5] += v.w*w0; acc[t0+4] += v.w*w1; acc[t0+3] += v.w*w2;
                }
            }
            float m = -1e30f;
            #pragma unroll
            for(int t=0;t<20;t++){ float v = acc[t+1]; m = fmaxf(m, v); }
            m += cb[oc];
            feat[(size_t)(tok0+tl)*KP_ + WORD_E_ + oc] = (unsigned short)f2bf(m);
        }
    } else if(blk < 1024+2432){
        // -------- word embedding into feat cols [0,300), zeros [330,352) --------
        int idx = (blk-1024)*256 + tid;
        int n = idx / 76, e4 = idx % 76;
        if(e4 < 75){
            float4 v = ((const float4*)(wt + (size_t)sent[n]*WORD_E_))[e4];
            unsigned int lo = f2bf(v.x) | (f2bf(v.y)<<16);
            unsigned int hi = f2bf(v.z) | (f2bf(v.w)<<16);
            uint2 pr; pr.x = lo; pr.y = hi;
            *(uint2*)(feat + (size_t)n*KP_ + e4*4) = pr;
        } else {
            unsigned int* z = (unsigned int*)(feat + (size_t)n*KP_ + 330);
            #pragma unroll
            for(int q=0;q<11;q++) z[q] = 0;
        }
    } else if(blk < 6272){
        // -------- pack w_ih (f then r) into bf16 (2048 x 352) --------
        int i = (blk-3456)*256 + tid;
        int r = i / KP_, k = i % KP_;
        const float* src = (r < G4_) ? wf : wr;
        int rr = r & (G4_-1);
        wpack[i] = (k < F_) ? (unsigned short)f2bf(src[(size_t)rr*F_ + k]) : 0;
    } else {
        if(tid == 0) *out = 0.f;
    }
}

// ---------------- bf16 MFMA GEMM: gx(bf16) = feat(8192x352) . wpack(2048x352)^T + bias ----------------
__global__ __launch_bounds__(256) void k_gemm(const unsigned short* A, const unsigned short* Bw,
                                              const float* bf, const float* br, unsigned short* gxb){
    __shared__ __align__(16) unsigned short As[64][40];
    __shared__ __align__(16) unsigned short Bs[64][40];
    int m0 = blockIdx.x*64, n0 = blockIdx.y*64;
    int tid = threadIdx.x;
    int w = tid>>6, lane = tid&63, q = lane>>4, l16 = lane&15;
    int srow = tid>>2, koff = (tid&3)*8;
    floatx4 acc0={0.f,0.f,0.f,0.f}, acc1=acc0, acc2=acc0, acc3=acc0;
    for(int k0=0; k0<KP_; k0+=32){
        uint4 av = *(const uint4*)(A  + (size_t)(m0+srow)*KP_ + k0 + koff);
        uint4 bv = *(const uint4*)(Bw + (size_t)(n0+srow)*KP_ + k0 + koff);
        __syncthreads();
        *(uint4*)&As[srow][koff] = av;
        *(uint4*)&Bs[srow][koff] = bv;
        __syncthreads();
        short8 af = *(const short8*)&As[w*16+l16][q*8];
        short8 b0 = *(const short8*)&Bs[l16][q*8];
        short8 b1 = *(const short8*)&Bs[16+l16][q*8];
        short8 b2 = *(const short8*)&Bs[32+l16][q*8];
        short8 b3 = *(const short8*)&Bs[48+l16][q*8];
        acc0 = __builtin_amdgcn_mfma_f32_16x16x32_bf16(af, b0, acc0, 0,0,0);
        acc1 = __builtin_amdgcn_mfma_f32_16x16x32_bf16(af, b1, acc1, 0,0,0);
        acc2 = __builtin_amdgcn_mfma_f32_16x16x32_bf16(af, b2, acc2, 0,0,0);
        acc3 = __builtin_amdgcn_mfma_f32_16x16x32_bf16(af, b3, acc3, 0,0,0);
    }
    #pragma unroll
    for(int nt=0; nt<4; nt++){
        floatx4 a = (nt==0)?acc0:(nt==1)?acc1:(nt==2)?acc2:acc3;
        int n = n0 + nt*16 + l16;
        int dirr = n >> 10, grow = n & 1023;
        float bias = dirr ? br[grow] : bf[grow];
        #pragma unroll
        for(int r=0; r<4; r++){
            int m = m0 + w*16 + q*4 + r;
            int b = m >> 7, s = m & 127;
            gxb[(((size_t)dirr*S_ + s)*B_ + b)*G4_ + grow] = (unsigned short)f2bf(a[r] + bias);
        }
    }
}

// ---------------- one LSTM step body (inlined) ----------------
__device__ __forceinline__ void lstm_step(
    const unsigned char* hbb, unsigned char* hwr_slot,
    float* wreg_lds, const int8v (*wreg)[2][2],
    int l16, int q, int cbl, int urel,
    unsigned int G0, unsigned int G1, unsigned int G2, unsigned int G3,
    float& cc, float* hseq_ptr, const float inv_sc)
{
    floatx4 a00={0.f,0.f,0.f,0.f}, a01=a00, a10=a00, a11=a00,
            a20=a00, a21=a00, a30=a00, a31=a00;
    #pragma unroll
    for(int ki=0; ki<2; ki++){
        int8v hb = *(const int8v*)&hbb[l16*272 + ki*128 + q*32];
        a00 = __builtin_amdgcn_mfma_scale_f32_16x16x128_f8f6f4(wreg[0][0][ki], hb, a00, 0,0,0,0x7F,0,0x7F);
        a01 = __builtin_amdgcn_mfma_scale_f32_16x16x128_f8f6f4(wreg[0][1][ki], hb, a01, 0,0,0,0x7F,0,0x7F);
        a10 = __builtin_amdgcn_mfma_scale_f32_16x16x128_f8f6f4(wreg[1][0][ki], hb, a10, 0,0,0,0x7F,0,0x7F);
        a11 = __builtin_amdgcn_mfma_scale_f32_16x16x128_f8f6f4(wreg[1][1][ki], hb, a11, 0,0,0,0x7F,0,0x7F);
        a20 = __builtin_amdgcn_mfma_scale_f32_16x16x128_f8f6f4(wreg[2][0][ki], hb, a20, 0,0,0,0x7F,0,0x7F);
        a21 = __builtin_amdgcn_mfma_scale_f32_16x16x128_f8f6f4(wreg[2][1][ki], hb, a21, 0,0,0,0x7F,0,0x7F);
        a30 = __builtin_amdgcn_mfma_scale_f32_16x16x128_f8f6f4(wreg[3][0][ki], hb, a30, 0,0,0,0x7F,0,0x7F);
        a31 = __builtin_amdgcn_mfma_scale_f32_16x16x128_f8f6f4(wreg[3][1][ki], hb, a31, 0,0,0,0x7F,0,0x7F);
    }
    // scatter to [g][batch(l16)][unit]: vectorized 16B LDS writes (2-way banked: free)
    if(l16 < 2){
        int base = l16*32 + q*4;
        *(floatx4*)&wreg_lds[0*64 + base     ] = a00;
        *(floatx4*)&wreg_lds[0*64 + base + 16] = a01;
        *(floatx4*)&wreg_lds[1*64 + base     ] = a10;
        *(floatx4*)&wreg_lds[1*64 + base + 16] = a11;
        *(floatx4*)&wreg_lds[2*64 + base     ] = a20;
        *(floatx4*)&wreg_lds[2*64 + base + 16] = a21;
        *(floatx4*)&wreg_lds[3*64 + base     ] = a30;
        *(floatx4*)&wreg_lds[3*64 + base + 16] = a31;
    }
    // same-wave ds write->read: DS pipe is in-order per wave; no barrier needed
    int cidx = cbl*32 + urel;
    float iv = wreg_lds[0*64 + cidx]*inv_sc + bf2f(G0);
    float fv = wreg_lds[1*64 + cidx]*inv_sc + bf2f(G1);
    float gv = wreg_lds[2*64 + cidx]*inv_sc + bf2f(G2);
    float ov = wreg_lds[3*64 + cidx]*inv_sc + bf2f(G3);
    float cn = sigmoidf_(fv)*cc + sigmoidf_(iv)*tanh_(gv);
    cc = cn;
    float hv = sigmoidf_(ov)*tanh_(cn);
    *hseq_ptr = hv;
    unsigned int hp8 = __builtin_amdgcn_cvt_pk_fp8_f32(hv*16.f, hv*16.f, 0u, false);
    *hwr_slot = (unsigned char)(hp8 & 0xFF);
    BAR_LDS();   // h(t) published; everyone past reads of the read-buffer
}

// ---------------- persistent biLSTM: 64 blocks x 512 threads (8 waves) ----------------
// block = (dir, 2-batch group). K=128 MX fp8 A-frags = 128 VGPR/lane. t-loop unrolled
// x2 with register rotation (no gc=gn copies -> gx prefetch survives the backedge).
// One lgkm-only barrier per step; gate xfer is intra-wave via per-wave LDS region.
__global__ __launch_bounds__(512,2) void k_lstm_all(const float* whhf, const float* whhr,
        const unsigned short* gxb, float* hseq)
{
    int bid = blockIdx.x;        // 0..63
    int dir = bid >> 5;
    int bg  = bid & 31;          // 2 batches: bg*2, bg*2+1
    int tid = threadIdx.x;
    int w    = tid >> 6;         // wave 0..7: units w*32..w*32+31
    int lane = tid & 63;
    int q    = lane >> 4;
    int l16  = lane & 15;

    __shared__ __align__(16) unsigned char hlds[2][16*272];   // [buf][batchrow][unit] fp8 (rows 2..15 = 0)
    __shared__ __align__(16) float wregion[8*256];            // per-wave gate xfer (8KB)

    const float* whh = dir ? whhr : whhf;

    // one-time: pack weight slice as K=128 fp8 A-fragments.
    // row = g*256 + w*32 + j*16 + l16 ; k = ki*128 + q*32 + byte (matches B-load)
    int8v wreg[4][2][2];   // [gate][j][ki] -> 128 VGPRs
    #pragma unroll
    for(int g=0; g<4; g++){
        #pragma unroll
        for(int j=0; j<2; j++){
            const float* rp = whh + (size_t)(g*H_ + w*32 + j*16 + l16)*H_;
            #pragma unroll
            for(int ki=0; ki<2; ki++){
                const float* p = rp + ki*128 + q*32;
                int8v acc;
                #pragma unroll
                for(int wd=0; wd<8; wd++){
                    unsigned int d = 0;
                    d = __builtin_amdgcn_cvt_pk_fp8_f32(p[wd*4+0]*64.f, p[wd*4+1]*64.f, d, false);
                    d = __builtin_amdgcn_cvt_pk_fp8_f32(p[wd*4+2]*64.f, p[wd*4+3]*64.f, d, true);
                    acc[wd] = (int)d;
                }
                wreg[g][j][ki] = acc;
            }
        }
    }

    for(int i = tid; i < 2*16*272/4; i += 512) ((unsigned int*)hlds)[i] = 0;
    __syncthreads();

    // cell role (intra-wave): lane = cbl*32 + urel; unit cu = w*32+urel, batch bg*2+cbl
    int urel = lane & 31;
    int cbl  = lane >> 5;        // 0..1
    int cu   = w*32 + urel;
    int b_glob = bg*2 + cbl;
    const float inv_sc = 1.0f/1024.f;   // w x64, h x16

    float cc = 0.f;
    const unsigned short* gbase = gxb + (size_t)dir*S_*B_*G4_ + (size_t)b_glob*G4_ + cu;
    float* hseq_base = hseq + ((size_t)dir*S_*B_ + b_glob)*H_ + cu;
    unsigned char* hw0 = &hlds[0][cbl*272 + cu];
    unsigned char* hw1 = &hlds[1][cbl*272 + cu];
    float* wreg_lds = &wregion[w*256];

    unsigned int p0,p1,p2,p3, q0,q1,q2,q3;
    {
        const unsigned short* gp = gbase + (size_t)(dir ? (S_-1) : 0)*B_*G4_;
        p0 = gp[0]; p1 = gp[256]; p2 = gp[512]; p3 = gp[768];
    }

    for(int t=0; t<S_; t+=2){
        int sA = dir ? (S_-1-t) : t;
        int sB = dir ? (S_-2-t) : (t+1);
        int sC = (t+2 < S_) ? (dir ? (S_-3-t) : (t+2)) : sB;   // dummy-safe

        // prefetch step t+1's gates (consumed after step A's MFMA block)
        {
            const unsigned short* gp = gbase + (size_t)sB*B_*G4_;
            q0 = gp[0]; q1 = gp[256]; q2 = gp[512]; q3 = gp[768];
        }
        // step A: read buf0, write buf1
        lstm_step(&hlds[0][0], hw1, wreg_lds, wreg, l16, q, cbl, urel,
                  p0,p1,p2,p3, cc, hseq_base + (size_t)sA*B_*H_, inv_sc);

        // prefetch step t+2's gates
        {
            const unsigned short* gp = gbase + (size_t)sC*B_*G4_;
            p0 = gp[0]; p1 = gp[256]; p2 = gp[512]; p3 = gp[768];
        }
        // step B: read buf1, write buf0
        lstm_step(&hlds[1][0], hw0, wreg_lds, wreg, l16, q, cbl, urel,
                  q0,q1,q2,q3, cc, hseq_base + (size_t)sB*B_*H_, inv_sc);
    }
}

// ---------------- emissions: block = 8 (s,b) pairs, h staged in LDS ----------------
__global__ __launch_bounds__(256) void k_em(const float* hseq, const float* lw, const float* lb, float* em){
    __shared__ __align__(16) float hb[8][516];   // +4 pad
    int sb0 = blockIdx.x*8;
    int tid = threadIdx.x;
    for(int i = tid; i < 1024; i += 256){
        int p = i >> 7, r = i & 127;
        int sb = sb0 + p, s = sb >> 6, b = sb & 63;
        const float* src = (r < 64) ? (hseq + (((size_t)0*S_+s)*B_+b)*H_ + r*4)
                                    : (hseq + (((size_t)1*S_+s)*B_+b)*H_ + (r-64)*4);
        *(float4*)&hb[p][r*4] = *(const float4*)src;
    }
    __syncthreads();
    if(tid < 200){
        int p = tid / 25, nc = tid % 25;
        const float4* wv = (const float4*)(lw + (size_t)nc*2*H_);
        const float4* hv = (const float4*)&hb[p][0];
        float acc = lb[nc];
        #pragma unroll 16
        for(int k=0;k<128;k++){ float4 a=hv[k], ww=wv[k]; acc += a.x*ww.x + a.y*ww.y + a.z*ww.z + a.w*ww.w; }
        em[(size_t)(sb0+p)*NC_ + nc] = acc;
    }
}

// ---------------- CRF NLL: one block = one WAVE (64 threads) per batch, no barriers ----------------
__global__ void k_crf(const float* em, const int* tag, const void* mask,
                      const float* st, const float* et, const float* tr, float* out){
    __shared__ float trs[NC_*NC_];
    int b = blockIdx.x, tid = threadIdx.x;
    for(int i=tid;i<NC_*NC_;i+=64) trs[i]=tr[i];
    unsigned int first = *(const unsigned int*)mask;
    int ml;  // 0=int32, 1=uint8, 2=float32
    if(first == 1u) ml = 0;
    else if(first == 0x3F800000u) ml = 2;
    else ml = 1;
    __syncthreads();

    // gold path score
    float part = 0.f; int cnt = 0;
    for(int s = tid; s < S_; s += 64){
        float mkv;
        {
            int off = b*S_ + s;
            if(ml==0)      mkv = ((const int*)mask)[off] ? 1.f : 0.f;
            else if(ml==1) mkv = ((const unsigned char*)mask)[off] ? 1.f : 0.f;
            else           mkv = ((const float*)mask)[off];
        }
        cnt += (mkv != 0.f) ? 1 : 0;
        if(s == 0){
            int t0 = tag[b*S_];
            part += st[t0] + em[((size_t)0*B_ + b)*NC_ + t0];
        } else {
            int tp = tag[b*S_ + s-1], tc = tag[b*S_ + s];
            part += mkv * (trs[tp*NC_ + tc] + em[((size_t)s*B_ + b)*NC_ + tc]);
        }
    }
    for(int o=32;o>0;o>>=1){ part += __shfl_down(part, o); cnt += __shfl_down(cnt, o); }
    float score = 0.f;
    int len = __shfl(cnt, 0);
    float score0 = __shfl(part, 0);
    if(tid == 0) score = score0 + et[ tag[b*S_ + len-1] ];

    // E columns in registers
    float Ecol[NC_];
    if(tid < NC_){
        #pragma unroll
        for(int i=0;i<NC_;i++) Ecol[i] = __expf(trs[i*NC_+tid]);
    } else {
        #pragma unroll
        for(int i=0;i<NC_;i++) Ecol[i] = 0.f;
    }

    float alpha = (tid < NC_) ? (st[tid] + em[((size_t)0*B_ + b)*NC_ + tid]) : -1e30f;
    float em_n = (tid < NC_) ? em[((size_t)1*B_ + b)*NC_ + tid] : 0.f;

    for(int s=1;s<S_;s++){
        float em_c = em_n;
        if(s+1 < S_) em_n = (tid < NC_) ? em[((size_t)(s+1)*B_ + b)*NC_ + tid] : 0.f;
        float mkv;
        {
            int off = b*S_ + s;
            if(ml==0)      mkv = ((const int*)mask)[off] ? 1.f : 0.f;
            else if(ml==1) mkv = ((const unsigned char*)mask)[off] ? 1.f : 0.f;
            else           mkv = ((const float*)mask)[off];
        }
        float v = alpha;
        for(int o=32;o>0;o>>=1) v = fmaxf(v, __shfl_down(v, o));
        float m = __shfl(v, 0);
        float a = (tid < NC_) ? __expf(alpha - m) : 0.f;
        float S = 0.f;
        #pragma unroll
        for(int i=0;i<NC_;i++){ S += __shfl(a, i) * Ecol[i]; }
        float nxt = m + __logf(S) + em_c;
        if(tid < NC_ && mkv != 0.f) alpha = nxt;
    }

    float v = (tid < NC_) ? (alpha + et[tid]) : -1e30f;
    float m2 = v;
    for(int o=32;o>0;o>>=1) m2 = fmaxf(m2, __shfl_down(m2, o));
    m2 = __shfl(m2, 0);
    float e = (tid < NC_) ? __expf(v - m2) : 0.f;
    for(int o=32;o>0;o>>=1) e += __shfl_down(e, o);
    if(tid == 0){
        float logZ = m2 + __logf(e);
        atomicAdd(out, logZ - score);
    }
}

extern "C" void kernel_launch(void* const* d_in, const int* in_sizes, int n_in,
                              void* d_out, int out_size, void* d_ws, size_t ws_size,
                              hipStream_t stream) {
    const float* word_table = (const float*)d_in[0];
    const float* char_table = (const float*)d_in[1];
    const float* conv_w     = (const float*)d_in[2];
    const float* conv_b     = (const float*)d_in[3];
    const float* w_ih_f     = (const float*)d_in[4];
    const float* w_hh_f     = (const float*)d_in[5];
    const float* b_f        = (const float*)d_in[6];
    const float* w_ih_r     = (const float*)d_in[7];
    const float* w_hh_r     = (const float*)d_in[8];
    const float* b_r        = (const float*)d_in[9];
    const float* lin_w      = (const float*)d_in[10];
    const float* lin_b      = (const float*)d_in[11];
    const float* start_t    = (const float*)d_in[12];
    const float* end_t      = (const float*)d_in[13];
    const float* trans      = (const float*)d_in[14];
    const int*   sent       = (const int*)d_in[15];
    const int*   word       = (const int*)d_in[16];
    const int*   tag        = (const int*)d_in[17];
    const void*  mask       = d_in[18];
    float* out = (float*)d_out;

    char* ws = (char*)d_ws;
    unsigned short* feat  = (unsigned short*)ws;                 // 8192*352*2   = 5,767,168 B
    unsigned short* wpack = (unsigned short*)(ws + 5767168);     // 2048*352*2   = 1,441,792 B
    unsigned short* gxb   = (unsigned short*)(ws + 5767168 + 1441792);           // 33,554,432 B
    float* hseq = (float*)(ws + 5767168 + 1441792 + 33554432);   // 16,777,216 B
    float* em   = (float*)(ws + 5767168 + 1441792 + 33554432 + 16777216);        // 204,800 f

    k_prep<<<dim3(6273), 256, 0, stream>>>(char_table, word, conv_w, conv_b,
                                           word_table, sent, w_ih_f, w_ih_r, out, feat, wpack);
    k_gemm<<<dim3(B_*S_/64, NG_/64), 256, 0, stream>>>(feat, wpack, b_f, b_r, gxb);
    k_lstm_all<<<dim3(64), 512, 0, stream>>>(w_hh_f, w_hh_r, gxb, hseq);
    k_em<<<dim3(S_*B_/8), 256, 0, stream>>>(hseq, lin_w, lin_b, em);
    k_crf<<<dim3(B_), 64, 0, stream>>>(em, tag, mask, start_t, end_t, trans, out);
}